// Round 8
// baseline (706.179 us; speedup 1.0000x reference)
//
#include <hip/hip_runtime.h>

constexpr int BB = 2, HH = 16, LL = 2048, DD = 128;
constexpr int QB = 128, KB = 32, NKT = LL / KB;  // 64 k-tiles
constexpr float SCALE = 0.08838834764831845f;    // 1/sqrt(128)

typedef __attribute__((ext_vector_type(8))) short bf16x8;
typedef __attribute__((ext_vector_type(8))) unsigned short u16x8;
typedef __attribute__((ext_vector_type(4))) float f32x4;

static __device__ __forceinline__ unsigned short f2bf(float f) {
  unsigned int u = __builtin_bit_cast(unsigned int, f);
  u += 0x7fffu + ((u >> 16) & 1u);   // RNE
  return (unsigned short)(u >> 16);
}
static __device__ __forceinline__ float bf2f(unsigned short h) {
  return __builtin_bit_cast(float, (unsigned int)h << 16);
}
static __device__ __forceinline__ int slotRC(int r) { return ((r >> 1) ^ (r >> 3)) & 3; }

#define GLD16(gsrc, ldst) __builtin_amdgcn_global_load_lds( \
    (const __attribute__((address_space(1))) void*)(gsrc), \
    (__attribute__((address_space(3))) void*)(ldst), 16, 0, 0)

// ---------------- prep ----------------
//   kbT tile [16 dslots][32 keys][8 d]  (bf16)  -> linear-DMA, 2-way LDS reads
//   vtT tile [4 kc][128 d][8 keys]      (bf16)  -> linear-DMA, 2-way LDS reads
//   cpw = bf16( mask ? probs*alpha : -1e30 )
__global__ __launch_bounds__(256)
void prep_kernel(const float* __restrict__ k, const float* __restrict__ v,
                 const int* __restrict__ mask, const float* __restrict__ probs,
                 const float* __restrict__ alphap,
                 unsigned short* __restrict__ kbT, unsigned short* __restrict__ vtT,
                 unsigned short* __restrict__ cpw)
{
  __shared__ unsigned short sT[128 * 40];   // V^T tile, 80 B rows
  const int bid = blockIdx.x;
  const int bh = bid >> 6, kt = bid & 63;
  const int t = threadIdx.x;
  const float alpha = alphap[0];
  const size_t tileBase = (size_t)bid * 4096;   // bid == bh*64 + kt
  const float* kg = k + ((size_t)bh * LL + kt * 32) * DD;
  const float* vg = v + ((size_t)bh * LL + kt * 32) * DD;

  // K -> 16B-block-transposed tile
  #pragma unroll
  for (int s = t; s < 512; s += 256) {
    int dsl = s >> 5, key = s & 31;
    const float* src = kg + key * DD + dsl * 8;
    float4 a = *(const float4*)src;
    float4 c = *(const float4*)(src + 4);
    u16x8 w;
    w[0] = f2bf(a.x); w[1] = f2bf(a.y); w[2] = f2bf(a.z); w[3] = f2bf(a.w);
    w[4] = f2bf(c.x); w[5] = f2bf(c.y); w[6] = f2bf(c.z); w[7] = f2bf(c.w);
    *(u16x8*)(kbT + tileBase + (size_t)s * 8) = w;
  }
  // V -> sT (transpose)
  #pragma unroll
  for (int i = 0; i < 4; ++i) {
    int idx = i * 256 + t;
    int key = idx >> 5, d4 = (idx & 31) * 4;
    float4 x = ((const float4*)vg)[idx];
    sT[(d4 + 0) * 40 + key] = f2bf(x.x);
    sT[(d4 + 1) * 40 + key] = f2bf(x.y);
    sT[(d4 + 2) * 40 + key] = f2bf(x.z);
    sT[(d4 + 3) * 40 + key] = f2bf(x.w);
  }
  // cpw (flat, bf16)
  {
    const float4* ps = (const float4*)probs;
    const int4* ms = (const int4*)mask;
    ushort4* cs = (ushort4*)cpw;
    size_t base = (size_t)bid * 1024;
    #pragma unroll
    for (int i = 0; i < 4; ++i) {
      size_t idx = base + i * 256 + t;
      float4 p = ps[idx];
      int4 m = ms[idx];
      ushort4 o;
      o.x = f2bf(m.x ? p.x * alpha : -1e30f);
      o.y = f2bf(m.y ? p.y * alpha : -1e30f);
      o.z = f2bf(m.z ? p.z * alpha : -1e30f);
      o.w = f2bf(m.w ? p.w * alpha : -1e30f);
      cs[idx] = o;
    }
  }
  __syncthreads();
  // sT -> vtT tile [kc][d][8]
  #pragma unroll
  for (int s = t; s < 512; s += 256) {
    int kc = s >> 7, d = s & 127;
    u16x8 w = *(const u16x8*)&sT[d * 40 + kc * 8];
    *(u16x8*)(vtT + tileBase + (size_t)s * 8) = w;
  }
}

// ---------------- main fused attention (QB=128, 1024 threads = 16 waves) ----------------
__global__ __launch_bounds__(1024, 8)
void attn_kernel(const float* __restrict__ q, const unsigned short* __restrict__ kbT,
                 const unsigned short* __restrict__ vtT, const unsigned short* __restrict__ cpw,
                 float* __restrict__ outA, float* __restrict__ outP)
{
  __shared__ unsigned short sK[2][4096];    // 16 KB dbuf, tile [dslot][key][8]
  __shared__ unsigned short sVt[2][4096];   // 16 KB dbuf, tile [kc][d][8]
  __shared__ unsigned short sP[QB * KB];    // 8 KB P tile (aliases sRed/sInv)
  float* sRedf = (float*)sP;                // 256 floats
  float* sInvf = sRedf + 256;               // 128 floats

  const int tid = threadIdx.x;
  const int lane = tid & 63;
  const int wid = tid >> 6;     // 0..15
  const int l15 = lane & 15;
  const int l4 = lane >> 4;
  const int wr = wid >> 1;      // 0..7 : q-row group (16 rows each)
  const int wc = wid & 1;       // 0..1 : key half (QK) / d half (PV)

  // XCD-chunked swizzle: XCD x (= bid%8) owns 64 consecutive work items
  // bh-major decode -> each XCD touches 4 bh.
  const int bid = blockIdx.x;
  const int work = ((bid & 7) << 6) | (bid >> 3);
  const int bh = work >> 4;     // 0..31
  const int qt = work & 15;     // 0..15
  const int b = bh >> 4;
  const int q0 = qt * QB;

  const unsigned short* kbh = kbT + (size_t)bh * 64 * 4096;
  const unsigned short* vbh = vtT + (size_t)bh * 64 * 4096;
  const unsigned short* cg = cpw + (size_t)b * LL * LL + (size_t)q0 * LL;
  float* oA = outA + (size_t)(bh * LL + q0) * DD;
  float* oP = outP + (size_t)bh * LL * LL + (size_t)q0 * LL;

  const int qrow = wr * 16 + l15;     // wave's q-row for A-frags (0..127)
  const int keyloc = wc * 16 + l15;   // wave's key column (QK B-frag)
  const int row0 = wr * 16 + l4 * 4;  // acc row base

  // ---- Q fragments straight from global (one-time, nt) ----
  bf16x8 qf0, qf1, qf2, qf3;
  {
    const float* qs = q + (size_t)(bh * LL + q0 + qrow) * DD + l4 * 8;
    #define LQ(FR, KC) { \
      f32x4 a = __builtin_nontemporal_load((const f32x4*)(qs + (KC) * 32)); \
      f32x4 c = __builtin_nontemporal_load((const f32x4*)(qs + (KC) * 32 + 4)); \
      FR[0]=(short)f2bf(a[0]); FR[1]=(short)f2bf(a[1]); FR[2]=(short)f2bf(a[2]); FR[3]=(short)f2bf(a[3]); \
      FR[4]=(short)f2bf(c[0]); FR[5]=(short)f2bf(c[1]); FR[6]=(short)f2bf(c[2]); FR[7]=(short)f2bf(c[3]); }
    LQ(qf0, 0) LQ(qf1, 1) LQ(qf2, 2) LQ(qf3, 3)
    #undef LQ
  }

  // wave-split DMA: waves 0-7 stage K, waves 8-15 stage V (8 KB each)
  const int ldsK = wid << 9;            // waves 0..7
  const int ldsV = (wid - 8) << 9;      // waves 8..15
  const int dmaT = tid & 511;
  #define DMA_K(BUF, KT) GLD16(kbh + (size_t)(KT) * 4096 + dmaT * 8, &sK[BUF][ldsK])
  #define DMA_V(BUF, KT) GLD16(vbh + (size_t)(KT) * 4096 + dmaT * 8, &sVt[BUF][ldsV])

  #define QKSTEP(KC, QF) { \
    bf16x8 bK = *(const bf16x8*)&sK[cur][(((KC) * 4 + l4) * 32 + keyloc) * 8]; \
    acc = __builtin_amdgcn_mfma_f32_16x16x32_bf16(QF, bK, acc, 0, 0, 0); }

  #define LDCP(CO) bf2f(__builtin_nontemporal_load(&cg[CO]))

  // =================== PASS A: rowsums ===================
  int co0 = (row0 + 0) * LL + keyloc;
  int co1 = co0 + LL, co2 = co1 + LL, co3 = co2 + LL;
  if (wid < 8) DMA_K(0, 0);
  float cn0 = LDCP(co0), cn1 = LDCP(co1), cn2 = LDCP(co2), cn3 = LDCP(co3);
  float sum0 = 0.f, sum1 = 0.f, sum2 = 0.f, sum3 = 0.f;
  for (int kt = 0; kt < NKT; ++kt) {
    const int cur = kt & 1;
    __syncthreads();                       // sK[cur] + cn* resident
    if (kt + 1 < NKT) {
      if (wid < 8) DMA_K(cur ^ 1, kt + 1);
    }
    float b0 = cn0, b1 = cn1, b2 = cn2, b3 = cn3;
    co0 += KB; co1 += KB; co2 += KB; co3 += KB;
    if (kt + 1 < NKT) { cn0 = LDCP(co0); cn1 = LDCP(co1); cn2 = LDCP(co2); cn3 = LDCP(co3); }
    f32x4 acc = {0.f, 0.f, 0.f, 0.f};
    QKSTEP(0, qf0) QKSTEP(1, qf1) QKSTEP(2, qf2) QKSTEP(3, qf3)
    sum0 += __expf(acc[0] * SCALE + b0);
    sum1 += __expf(acc[1] * SCALE + b1);
    sum2 += __expf(acc[2] * SCALE + b2);
    sum3 += __expf(acc[3] * SCALE + b3);
  }

  #pragma unroll
  for (int m = 1; m < 16; m <<= 1) {
    sum0 += __shfl_xor(sum0, m, 64);
    sum1 += __shfl_xor(sum1, m, 64);
    sum2 += __shfl_xor(sum2, m, 64);
    sum3 += __shfl_xor(sum3, m, 64);
  }
  __syncthreads();
  if (l15 == 0) {
    sRedf[(row0 + 0) * 2 + wc] = sum0;
    sRedf[(row0 + 1) * 2 + wc] = sum1;
    sRedf[(row0 + 2) * 2 + wc] = sum2;
    sRedf[(row0 + 3) * 2 + wc] = sum3;
  }
  __syncthreads();
  if (tid < QB) sInvf[tid] = 1.0f / (sRedf[tid * 2] + sRedf[tid * 2 + 1]);
  __syncthreads();
  const float inv0 = sInvf[row0 + 0], inv1 = sInvf[row0 + 1],
              inv2 = sInvf[row0 + 2], inv3 = sInvf[row0 + 3];

  // =================== PASS B: attn_p + O ===================
  co0 = (row0 + 0) * LL + keyloc;
  co1 = co0 + LL; co2 = co1 + LL; co3 = co2 + LL;
  __syncthreads();   // all sInv reads done before sP reuse
  if (wid < 8) DMA_K(0, 0); else DMA_V(0, 0);
  cn0 = LDCP(co0); cn1 = LDCP(co1); cn2 = LDCP(co2); cn3 = LDCP(co3);
  f32x4 o0 = {0,0,0,0}, o1 = {0,0,0,0}, o2 = {0,0,0,0}, o3 = {0,0,0,0};
  for (int kt = 0; kt < NKT; ++kt) {
    const int cur = kt & 1;
    __syncthreads();                       // sK/sVt[cur] + cn* resident; sP free
    if (kt + 1 < NKT) {
      if (wid < 8) DMA_K(cur ^ 1, kt + 1); else DMA_V(cur ^ 1, kt + 1);
    }
    float b0 = cn0, b1 = cn1, b2 = cn2, b3 = cn3;
    co0 += KB; co1 += KB; co2 += KB; co3 += KB;
    if (kt + 1 < NKT) { cn0 = LDCP(co0); cn1 = LDCP(co1); cn2 = LDCP(co2); cn3 = LDCP(co3); }
    f32x4 acc = {0.f, 0.f, 0.f, 0.f};
    QKSTEP(0, qf0) QKSTEP(1, qf1) QKSTEP(2, qf2) QKSTEP(3, qf3)
    float e0 = __expf(acc[0] * SCALE + b0) * inv0;
    float e1 = __expf(acc[1] * SCALE + b1) * inv1;
    float e2 = __expf(acc[2] * SCALE + b2) * inv2;
    float e3 = __expf(acc[3] * SCALE + b3) * inv3;
    const int keyg = kt * KB + keyloc;
    __builtin_nontemporal_store(e0, &oP[(size_t)(row0 + 0) * LL + keyg]);
    __builtin_nontemporal_store(e1, &oP[(size_t)(row0 + 1) * LL + keyg]);
    __builtin_nontemporal_store(e2, &oP[(size_t)(row0 + 2) * LL + keyg]);
    __builtin_nontemporal_store(e3, &oP[(size_t)(row0 + 3) * LL + keyg]);
    sP[(row0 + 0) * KB + (keyloc ^ (slotRC(row0 + 0) << 3))] = f2bf(e0);
    sP[(row0 + 1) * KB + (keyloc ^ (slotRC(row0 + 1) << 3))] = f2bf(e1);
    sP[(row0 + 2) * KB + (keyloc ^ (slotRC(row0 + 2) << 3))] = f2bf(e2);
    sP[(row0 + 3) * KB + (keyloc ^ (slotRC(row0 + 3) << 3))] = f2bf(e3);
    // mid barrier: LDS visibility only — DMA + cpm prefetch stay in flight
    asm volatile("s_waitcnt lgkmcnt(0)\n\ts_barrier" ::: "memory");
    bf16x8 aP = *(const bf16x8*)&sP[qrow * KB + ((l4 * 8) ^ (slotRC(qrow) << 3))];
    #define PVSTEP(DT, OO) { \
      int dcol = wc * 64 + (DT) * 16 + l15; \
      bf16x8 bV = *(const bf16x8*)&sVt[cur][(l4 * 128 + dcol) * 8]; \
      OO = __builtin_amdgcn_mfma_f32_16x16x32_bf16(aP, bV, OO, 0, 0, 0); }
    PVSTEP(0, o0) PVSTEP(1, o1) PVSTEP(2, o2) PVSTEP(3, o3)
    #undef PVSTEP
  }

  // ---- store attention (non-temporal) ----
  #pragma unroll
  for (int r = 0; r < 4; ++r) {
    float* dst = oA + (size_t)(row0 + r) * DD + wc * 64 + l15;
    __builtin_nontemporal_store(o0[r], dst);
    __builtin_nontemporal_store(o1[r], dst + 16);
    __builtin_nontemporal_store(o2[r], dst + 32);
    __builtin_nontemporal_store(o3[r], dst + 48);
  }
}

extern "C" void kernel_launch(void* const* d_in, const int* in_sizes, int n_in,
                              void* d_out, int out_size, void* d_ws, size_t ws_size,
                              hipStream_t stream) {
  const float* q = (const float*)d_in[0];
  const float* k = (const float*)d_in[1];
  const float* v = (const float*)d_in[2];
  const int* mask = (const int*)d_in[3];
  const float* probs = (const float*)d_in[4];
  const float* alpha = (const float*)d_in[5];
  float* outA = (float*)d_out;
  float* outP = outA + (size_t)BB * HH * LL * DD;
  unsigned short* kbT = (unsigned short*)d_ws;
  unsigned short* vtT = kbT + (size_t)32 * 64 * 4096;
  unsigned short* cpw = vtT + (size_t)32 * 64 * 4096;
  hipLaunchKernelGGL(prep_kernel, dim3(32 * 64), dim3(256), 0, stream,
                     k, v, mask, probs, alpha, kbT, vtT, cpw);
  hipLaunchKernelGGL(attn_kernel, dim3(BB * HH * (LL / QB)), dim3(1024), 0, stream,
                     q, kbT, vtT, cpw, outA, outP);
}

// Round 9
// 594.904 us; speedup vs baseline: 1.1870x; 1.1870x over previous
//
#include <hip/hip_runtime.h>

constexpr int BB = 2, HH = 16, LL = 2048, DD = 128;
constexpr int QB = 64, KB = 32, NKT = LL / KB;   // 64 k-tiles
constexpr float SCALE = 0.08838834764831845f;    // 1/sqrt(128)

typedef __attribute__((ext_vector_type(8))) short bf16x8;
typedef __attribute__((ext_vector_type(8))) unsigned short u16x8;
typedef __attribute__((ext_vector_type(4))) float f32x4;

static __device__ __forceinline__ unsigned short f2bf(float f) {
  unsigned int u = __builtin_bit_cast(unsigned int, f);
  u += 0x7fffu + ((u >> 16) & 1u);   // RNE
  return (unsigned short)(u >> 16);
}
static __device__ __forceinline__ float bf2f(unsigned short h) {
  return __builtin_bit_cast(float, (unsigned int)h << 16);
}
static __device__ __forceinline__ int slotRC(int r) { return ((r >> 1) ^ (r >> 3)) & 3; }

#define GLD16(gsrc, ldst) __builtin_amdgcn_global_load_lds( \
    (const __attribute__((address_space(1))) void*)(gsrc), \
    (__attribute__((address_space(3))) void*)(ldst), 16, 0, 0)

// ---------------- prep ----------------
//   kbT tile [16 dslots][32 keys][8 d]  (bf16)  -> linear-DMA, 2-way LDS reads
//   vtT tile [4 kc][128 d][8 keys]      (bf16)  -> linear-DMA, 2-way LDS reads
//   cpw = bf16( mask ? probs*alpha : -1e30 )    (16.7 MB -> L3-resident, shared by 16 heads)
__global__ __launch_bounds__(256)
void prep_kernel(const float* __restrict__ k, const float* __restrict__ v,
                 const int* __restrict__ mask, const float* __restrict__ probs,
                 const float* __restrict__ alphap,
                 unsigned short* __restrict__ kbT, unsigned short* __restrict__ vtT,
                 unsigned short* __restrict__ cpw)
{
  __shared__ unsigned short sT[128 * 40];   // V^T tile, 80 B rows
  const int bid = blockIdx.x;
  const int bh = bid >> 6, kt = bid & 63;
  const int t = threadIdx.x;
  const float alpha = alphap[0];
  const size_t tileBase = (size_t)bid * 4096;   // bid == bh*64 + kt
  const float* kg = k + ((size_t)bh * LL + kt * 32) * DD;
  const float* vg = v + ((size_t)bh * LL + kt * 32) * DD;

  // K -> 16B-block-transposed tile
  #pragma unroll
  for (int s = t; s < 512; s += 256) {
    int dsl = s >> 5, key = s & 31;
    const float* src = kg + key * DD + dsl * 8;
    float4 a = *(const float4*)src;
    float4 c = *(const float4*)(src + 4);
    u16x8 w;
    w[0] = f2bf(a.x); w[1] = f2bf(a.y); w[2] = f2bf(a.z); w[3] = f2bf(a.w);
    w[4] = f2bf(c.x); w[5] = f2bf(c.y); w[6] = f2bf(c.z); w[7] = f2bf(c.w);
    *(u16x8*)(kbT + tileBase + (size_t)s * 8) = w;
  }
  // V -> sT (transpose)
  #pragma unroll
  for (int i = 0; i < 4; ++i) {
    int idx = i * 256 + t;
    int key = idx >> 5, d4 = (idx & 31) * 4;
    float4 x = ((const float4*)vg)[idx];
    sT[(d4 + 0) * 40 + key] = f2bf(x.x);
    sT[(d4 + 1) * 40 + key] = f2bf(x.y);
    sT[(d4 + 2) * 40 + key] = f2bf(x.z);
    sT[(d4 + 3) * 40 + key] = f2bf(x.w);
  }
  // cpw (flat, bf16)
  {
    const float4* ps = (const float4*)probs;
    const int4* ms = (const int4*)mask;
    ushort4* cs = (ushort4*)cpw;
    size_t base = (size_t)bid * 1024;
    #pragma unroll
    for (int i = 0; i < 4; ++i) {
      size_t idx = base + i * 256 + t;
      float4 p = ps[idx];
      int4 m = ms[idx];
      ushort4 o;
      o.x = f2bf(m.x ? p.x * alpha : -1e30f);
      o.y = f2bf(m.y ? p.y * alpha : -1e30f);
      o.z = f2bf(m.z ? p.z * alpha : -1e30f);
      o.w = f2bf(m.w ? p.w * alpha : -1e30f);
      cs[idx] = o;
    }
  }
  __syncthreads();
  // sT -> vtT tile [kc][d][8]
  #pragma unroll
  for (int s = t; s < 512; s += 256) {
    int kc = s >> 7, d = s & 127;
    u16x8 w = *(const u16x8*)&sT[d * 40 + kc * 8];
    *(u16x8*)(vtT + tileBase + (size_t)s * 8) = w;
  }
}

// ---------------- main fused attention (QB=64, 512 threads = 8 waves) ----------------
__global__ __launch_bounds__(512, 8)
void attn_kernel(const float* __restrict__ q, const unsigned short* __restrict__ kbT,
                 const unsigned short* __restrict__ vtT, const unsigned short* __restrict__ cpw,
                 float* __restrict__ outA, float* __restrict__ outP)
{
  __shared__ unsigned short sK[2][4096];    // 16 KB dbuf, tile [dslot][key][8]
  __shared__ unsigned short sVt[2][4096];   // 16 KB dbuf, tile [kc][d][8]
  __shared__ unsigned short sP[2048];       // 4 KB P tile (aliases sRed/sInv)
  float* sRedf = (float*)sP;
  float* sInvf = sRedf + 128;

  const int tid = threadIdx.x;
  const int lane = tid & 63;
  const int wid = tid >> 6;
  const int l15 = lane & 15;
  const int l4 = lane >> 4;
  const int wr = wid >> 1, wc = wid & 1;

  // XCD-chunked swizzle: XCD x (= bid%8) owns work [x*128, x*128+128)
  // bh-major decode -> each XCD touches 4 bh (K+V ws ~8 MB vs 4 MB L2 + L3 backstop)
  const int bid = blockIdx.x;
  const int work = ((bid & 7) << 7) | (bid >> 3);
  const int bh = work >> 5;     // 0..31
  const int qt = work & 31;     // 0..31
  const int b = bh >> 4;
  const int q0 = qt * QB;

  const unsigned short* kbh = kbT + (size_t)bh * 64 * 4096;
  const unsigned short* vbh = vtT + (size_t)bh * 64 * 4096;
  const unsigned short* cg = cpw + (size_t)b * LL * LL + (size_t)q0 * LL;
  float* oA = outA + (size_t)(bh * LL + q0) * DD;
  float* oP = outP + (size_t)bh * LL * LL + (size_t)q0 * LL;

  const int qrow = wr * 16 + l15;     // wave's q-row for A-frags
  const int keyloc = wc * 16 + l15;   // wave's key column (QK B-frag)
  const int row0 = wr * 16 + l4 * 4;  // acc row base

  // ---- Q fragments straight from global (one-time) ----
  bf16x8 qf0, qf1, qf2, qf3;
  {
    const float* qs = q + (size_t)(bh * LL + q0 + qrow) * DD + l4 * 8;
    #define LQ(FR, KC) { \
      float4 a = *(const float4*)(qs + (KC) * 32); \
      float4 c = *(const float4*)(qs + (KC) * 32 + 4); \
      FR[0]=(short)f2bf(a.x); FR[1]=(short)f2bf(a.y); FR[2]=(short)f2bf(a.z); FR[3]=(short)f2bf(a.w); \
      FR[4]=(short)f2bf(c.x); FR[5]=(short)f2bf(c.y); FR[6]=(short)f2bf(c.z); FR[7]=(short)f2bf(c.w); }
    LQ(qf0, 0) LQ(qf1, 1) LQ(qf2, 2) LQ(qf3, 3)
    #undef LQ
  }

  const int ldsW = wid << 9;   // u16 elements: 1 KB per wave
  #define DMA_K(BUF, KT) GLD16(kbh + (size_t)(KT) * 4096 + tid * 8, &sK[BUF][ldsW])
  #define DMA_V(BUF, KT) GLD16(vbh + (size_t)(KT) * 4096 + tid * 8, &sVt[BUF][ldsW])

  #define QKSTEP(KC, QF) { \
    bf16x8 bK = *(const bf16x8*)&sK[cur][(((KC) * 4 + l4) * 32 + keyloc) * 8]; \
    acc = __builtin_amdgcn_mfma_f32_16x16x32_bf16(QF, bK, acc, 0, 0, 0); }

  #define LDCP(CO) bf2f(cg[CO])   // cached load: cpw shared by all 16 heads of b

  // =================== PASS A: rowsums ===================
  int co0 = (row0 + 0) * LL + keyloc;
  int co1 = co0 + LL, co2 = co1 + LL, co3 = co2 + LL;
  DMA_K(0, 0);
  float cn0 = LDCP(co0), cn1 = LDCP(co1), cn2 = LDCP(co2), cn3 = LDCP(co3);
  float sum0 = 0.f, sum1 = 0.f, sum2 = 0.f, sum3 = 0.f;
  for (int kt = 0; kt < NKT; ++kt) {
    const int cur = kt & 1;
    __syncthreads();                       // sK[cur] + cn* resident
    if (kt + 1 < NKT) DMA_K(cur ^ 1, kt + 1);
    float b0 = cn0, b1 = cn1, b2 = cn2, b3 = cn3;
    co0 += KB; co1 += KB; co2 += KB; co3 += KB;
    if (kt + 1 < NKT) { cn0 = LDCP(co0); cn1 = LDCP(co1); cn2 = LDCP(co2); cn3 = LDCP(co3); }
    f32x4 acc = {0.f, 0.f, 0.f, 0.f};
    QKSTEP(0, qf0) QKSTEP(1, qf1) QKSTEP(2, qf2) QKSTEP(3, qf3)
    sum0 += __expf(acc[0] * SCALE + b0);
    sum1 += __expf(acc[1] * SCALE + b1);
    sum2 += __expf(acc[2] * SCALE + b2);
    sum3 += __expf(acc[3] * SCALE + b3);
  }

  #pragma unroll
  for (int m = 1; m < 16; m <<= 1) {
    sum0 += __shfl_xor(sum0, m, 64);
    sum1 += __shfl_xor(sum1, m, 64);
    sum2 += __shfl_xor(sum2, m, 64);
    sum3 += __shfl_xor(sum3, m, 64);
  }
  __syncthreads();
  if (l15 == 0) {
    sRedf[(row0 + 0) * 2 + wc] = sum0;
    sRedf[(row0 + 1) * 2 + wc] = sum1;
    sRedf[(row0 + 2) * 2 + wc] = sum2;
    sRedf[(row0 + 3) * 2 + wc] = sum3;
  }
  __syncthreads();
  if (tid < QB) sInvf[tid] = 1.0f / (sRedf[tid * 2] + sRedf[tid * 2 + 1]);
  __syncthreads();
  const float inv0 = sInvf[row0 + 0], inv1 = sInvf[row0 + 1],
              inv2 = sInvf[row0 + 2], inv3 = sInvf[row0 + 3];

  // =================== PASS B: attn_p + O ===================
  co0 = (row0 + 0) * LL + keyloc;
  co1 = co0 + LL; co2 = co1 + LL; co3 = co2 + LL;
  __syncthreads();   // sInv reads done before sP reuse
  DMA_K(0, 0); DMA_V(0, 0);
  cn0 = LDCP(co0); cn1 = LDCP(co1); cn2 = LDCP(co2); cn3 = LDCP(co3);
  f32x4 o0 = {0,0,0,0}, o1 = {0,0,0,0}, o2 = {0,0,0,0}, o3 = {0,0,0,0};
  for (int kt = 0; kt < NKT; ++kt) {
    const int cur = kt & 1;
    __syncthreads();                       // sK/sVt[cur] + cn* resident; sP free
    if (kt + 1 < NKT) { DMA_K(cur ^ 1, kt + 1); DMA_V(cur ^ 1, kt + 1); }
    float b0 = cn0, b1 = cn1, b2 = cn2, b3 = cn3;
    co0 += KB; co1 += KB; co2 += KB; co3 += KB;
    if (kt + 1 < NKT) { cn0 = LDCP(co0); cn1 = LDCP(co1); cn2 = LDCP(co2); cn3 = LDCP(co3); }
    f32x4 acc = {0.f, 0.f, 0.f, 0.f};
    QKSTEP(0, qf0) QKSTEP(1, qf1) QKSTEP(2, qf2) QKSTEP(3, qf3)
    float e0 = __expf(acc[0] * SCALE + b0) * inv0;
    float e1 = __expf(acc[1] * SCALE + b1) * inv1;
    float e2 = __expf(acc[2] * SCALE + b2) * inv2;
    float e3 = __expf(acc[3] * SCALE + b3) * inv3;
    const int keyg = kt * KB + keyloc;
    // non-temporal: keep the 537 MB attn_p stream from evicting L2/L3 reads
    __builtin_nontemporal_store(e0, &oP[(size_t)(row0 + 0) * LL + keyg]);
    __builtin_nontemporal_store(e1, &oP[(size_t)(row0 + 1) * LL + keyg]);
    __builtin_nontemporal_store(e2, &oP[(size_t)(row0 + 2) * LL + keyg]);
    __builtin_nontemporal_store(e3, &oP[(size_t)(row0 + 3) * LL + keyg]);
    sP[(row0 + 0) * KB + (keyloc ^ (slotRC(row0 + 0) << 3))] = f2bf(e0);
    sP[(row0 + 1) * KB + (keyloc ^ (slotRC(row0 + 1) << 3))] = f2bf(e1);
    sP[(row0 + 2) * KB + (keyloc ^ (slotRC(row0 + 2) << 3))] = f2bf(e2);
    sP[(row0 + 3) * KB + (keyloc ^ (slotRC(row0 + 3) << 3))] = f2bf(e3);
    // mid barrier: LDS visibility only — DMA + cpw prefetch stay in flight
    asm volatile("s_waitcnt lgkmcnt(0)\n\ts_barrier" ::: "memory");
    bf16x8 aP = *(const bf16x8*)&sP[qrow * KB + ((l4 * 8) ^ (slotRC(qrow) << 3))];
    #define PVSTEP(DT, OO) { \
      int dcol = wc * 64 + (DT) * 16 + l15; \
      bf16x8 bV = *(const bf16x8*)&sVt[cur][(l4 * 128 + dcol) * 8]; \
      OO = __builtin_amdgcn_mfma_f32_16x16x32_bf16(aP, bV, OO, 0, 0, 0); }
    PVSTEP(0, o0) PVSTEP(1, o1) PVSTEP(2, o2) PVSTEP(3, o3)
    #undef PVSTEP
  }

  // ---- store attention (non-temporal) ----
  #pragma unroll
  for (int r = 0; r < 4; ++r) {
    float* dst = oA + (size_t)(row0 + r) * DD + wc * 64 + l15;
    __builtin_nontemporal_store(o0[r], dst);
    __builtin_nontemporal_store(o1[r], dst + 16);
    __builtin_nontemporal_store(o2[r], dst + 32);
    __builtin_nontemporal_store(o3[r], dst + 48);
  }
}

extern "C" void kernel_launch(void* const* d_in, const int* in_sizes, int n_in,
                              void* d_out, int out_size, void* d_ws, size_t ws_size,
                              hipStream_t stream) {
  const float* q = (const float*)d_in[0];
  const float* k = (const float*)d_in[1];
  const float* v = (const float*)d_in[2];
  const int* mask = (const int*)d_in[3];
  const float* probs = (const float*)d_in[4];
  const float* alpha = (const float*)d_in[5];
  float* outA = (float*)d_out;
  float* outP = outA + (size_t)BB * HH * LL * DD;
  unsigned short* kbT = (unsigned short*)d_ws;
  unsigned short* vtT = kbT + (size_t)32 * 64 * 4096;
  unsigned short* cpw = vtT + (size_t)32 * 64 * 4096;
  hipLaunchKernelGGL(prep_kernel, dim3(32 * 64), dim3(256), 0, stream,
                     k, v, mask, probs, alpha, kbT, vtT, cpw);
  hipLaunchKernelGGL(attn_kernel, dim3(BB * HH * (LL / QB)), dim3(512), 0, stream,
                     q, kbT, vtT, cpw, outA, outP);
}

// Round 10
// 517.405 us; speedup vs baseline: 1.3648x; 1.1498x over previous
//
#include <hip/hip_runtime.h>

constexpr int BB = 2, HH = 16, LL = 2048, DD = 128;
constexpr int QB = 128, KB = 32, NKT = LL / KB;  // 64 k-tiles
constexpr float SCALE = 0.08838834764831845f;    // 1/sqrt(128)

typedef __attribute__((ext_vector_type(8))) short bf16x8;
typedef __attribute__((ext_vector_type(8))) unsigned short u16x8;
typedef __attribute__((ext_vector_type(4))) float f32x4;

static __device__ __forceinline__ unsigned short f2bf(float f) {
  unsigned int u = __builtin_bit_cast(unsigned int, f);
  u += 0x7fffu + ((u >> 16) & 1u);   // RNE
  return (unsigned short)(u >> 16);
}
static __device__ __forceinline__ int slotRC(int r) { return ((r >> 1) ^ (r >> 3)) & 3; }

#define GLD16(gsrc, ldst) __builtin_amdgcn_global_load_lds( \
    (const __attribute__((address_space(1))) void*)(gsrc), \
    (__attribute__((address_space(3))) void*)(ldst), 16, 0, 0)

// ---------------- prep ----------------
//   kbT tile [16 dslots][32 keys][8 d]  (bf16)  -> linear-DMA, 2-way LDS reads
//   vtT tile [4 kc][128 d][8 keys]      (bf16)  -> linear-DMA, 2-way LDS reads
//   cpm = mask ? probs*alpha : -1e30    (fp32 — bf16 scalar loads waste sectors, r9)
__global__ __launch_bounds__(256)
void prep_kernel(const float* __restrict__ k, const float* __restrict__ v,
                 const int* __restrict__ mask, const float* __restrict__ probs,
                 const float* __restrict__ alphap,
                 unsigned short* __restrict__ kbT, unsigned short* __restrict__ vtT,
                 float* __restrict__ cpm)
{
  __shared__ unsigned short sT[128 * 40];   // V^T tile, 80 B rows
  const int bid = blockIdx.x;
  const int bh = bid >> 6, kt = bid & 63;
  const int t = threadIdx.x;
  const float alpha = alphap[0];
  const size_t tileBase = (size_t)bid * 4096;   // bid == bh*64 + kt
  const float* kg = k + ((size_t)bh * LL + kt * 32) * DD;
  const float* vg = v + ((size_t)bh * LL + kt * 32) * DD;

  // K -> 16B-block-transposed tile
  #pragma unroll
  for (int s = t; s < 512; s += 256) {
    int dsl = s >> 5, key = s & 31;
    const float* src = kg + key * DD + dsl * 8;
    float4 a = *(const float4*)src;
    float4 c = *(const float4*)(src + 4);
    u16x8 w;
    w[0] = f2bf(a.x); w[1] = f2bf(a.y); w[2] = f2bf(a.z); w[3] = f2bf(a.w);
    w[4] = f2bf(c.x); w[5] = f2bf(c.y); w[6] = f2bf(c.z); w[7] = f2bf(c.w);
    *(u16x8*)(kbT + tileBase + (size_t)s * 8) = w;
  }
  // V -> sT (transpose)
  #pragma unroll
  for (int i = 0; i < 4; ++i) {
    int idx = i * 256 + t;
    int key = idx >> 5, d4 = (idx & 31) * 4;
    float4 x = ((const float4*)vg)[idx];
    sT[(d4 + 0) * 40 + key] = f2bf(x.x);
    sT[(d4 + 1) * 40 + key] = f2bf(x.y);
    sT[(d4 + 2) * 40 + key] = f2bf(x.z);
    sT[(d4 + 3) * 40 + key] = f2bf(x.w);
  }
  // cpm (flat, fp32)
  {
    const float4* ps = (const float4*)probs;
    const int4* ms = (const int4*)mask;
    float4* cs = (float4*)cpm;
    size_t base = (size_t)bid * 1024;
    #pragma unroll
    for (int i = 0; i < 4; ++i) {
      size_t idx = base + i * 256 + t;
      float4 p = ps[idx];
      int4 m = ms[idx];
      float4 o;
      o.x = m.x ? p.x * alpha : -1e30f;
      o.y = m.y ? p.y * alpha : -1e30f;
      o.z = m.z ? p.z * alpha : -1e30f;
      o.w = m.w ? p.w * alpha : -1e30f;
      cs[idx] = o;
    }
  }
  __syncthreads();
  // sT -> vtT tile [kc][d][8]
  #pragma unroll
  for (int s = t; s < 512; s += 256) {
    int kc = s >> 7, d = s & 127;
    u16x8 w = *(const u16x8*)&sT[d * 40 + kc * 8];
    *(u16x8*)(vtT + tileBase + (size_t)s * 8) = w;
  }
}

// ---------------- main fused attention (QB=128, 1024 threads = 16 waves) ----------------
__global__ __launch_bounds__(1024, 8)
void attn_kernel(const float* __restrict__ q, const unsigned short* __restrict__ kbT,
                 const unsigned short* __restrict__ vtT, const float* __restrict__ cpm,
                 float* __restrict__ outA, float* __restrict__ outP)
{
  __shared__ unsigned short sK[2][4096];    // 16 KB dbuf, tile [dslot][key][8]
  __shared__ unsigned short sVt[2][4096];   // 16 KB dbuf, tile [kc][d][8]
  __shared__ unsigned short sP[QB * KB];    // 8 KB P tile (aliases sRed/sInv)
  float* sRedf = (float*)sP;                // 256 floats
  float* sInvf = sRedf + 256;               // 128 floats

  const int tid = threadIdx.x;
  const int lane = tid & 63;
  const int wid = tid >> 6;     // 0..15
  const int l15 = lane & 15;
  const int l4 = lane >> 4;
  const int wr = wid >> 1;      // 0..7 : q-row group (16 rows each)
  const int wc = wid & 1;       // 0..1 : key half (QK) / d half (PV)

  // XCD-chunked swizzle: XCD x (= bid%8) owns 64 consecutive work items
  // bh-major decode -> each XCD touches 4 bh.
  const int bid = blockIdx.x;
  const int work = ((bid & 7) << 6) | (bid >> 3);
  const int bh = work >> 4;     // 0..31
  const int qt = work & 15;     // 0..15
  const int b = bh >> 4;
  const int q0 = qt * QB;

  const unsigned short* kbh = kbT + (size_t)bh * 64 * 4096;
  const unsigned short* vbh = vtT + (size_t)bh * 64 * 4096;
  const float* cg = cpm + (size_t)b * LL * LL + (size_t)q0 * LL;
  float* oA = outA + (size_t)(bh * LL + q0) * DD;
  float* oP = outP + (size_t)bh * LL * LL + (size_t)q0 * LL;

  const int qrow = wr * 16 + l15;     // wave's q-row for A-frags (0..127)
  const int keyloc = wc * 16 + l15;   // wave's key column (QK B-frag)
  const int row0 = wr * 16 + l4 * 4;  // acc row base

  // ---- Q fragments straight from global (one-time) ----
  bf16x8 qf0, qf1, qf2, qf3;
  {
    const float* qs = q + (size_t)(bh * LL + q0 + qrow) * DD + l4 * 8;
    #define LQ(FR, KC) { \
      float4 a = *(const float4*)(qs + (KC) * 32); \
      float4 c = *(const float4*)(qs + (KC) * 32 + 4); \
      FR[0]=(short)f2bf(a.x); FR[1]=(short)f2bf(a.y); FR[2]=(short)f2bf(a.z); FR[3]=(short)f2bf(a.w); \
      FR[4]=(short)f2bf(c.x); FR[5]=(short)f2bf(c.y); FR[6]=(short)f2bf(c.z); FR[7]=(short)f2bf(c.w); }
    LQ(qf0, 0) LQ(qf1, 1) LQ(qf2, 2) LQ(qf3, 3)
    #undef LQ
  }

  // wave-split DMA: waves 0-7 stage K, waves 8-15 stage V (8 KB each)
  const int ldsK = wid << 9;            // waves 0..7
  const int ldsV = (wid - 8) << 9;      // waves 8..15
  const int dmaT = tid & 511;
  #define DMA_K(BUF, KT) GLD16(kbh + (size_t)(KT) * 4096 + dmaT * 8, &sK[BUF][ldsK])
  #define DMA_V(BUF, KT) GLD16(vbh + (size_t)(KT) * 4096 + dmaT * 8, &sVt[BUF][ldsV])

  #define QKSTEP(KC, QF) { \
    bf16x8 bK = *(const bf16x8*)&sK[cur][(((KC) * 4 + l4) * 32 + keyloc) * 8]; \
    acc = __builtin_amdgcn_mfma_f32_16x16x32_bf16(QF, bK, acc, 0, 0, 0); }

  #define LDCP(CO) (cg[CO])   // cached fp32: shared by 16 heads, good sector use

  // =================== PASS A: rowsums ===================
  int co0 = (row0 + 0) * LL + keyloc;
  int co1 = co0 + LL, co2 = co1 + LL, co3 = co2 + LL;
  if (wid < 8) DMA_K(0, 0);
  float cn0 = LDCP(co0), cn1 = LDCP(co1), cn2 = LDCP(co2), cn3 = LDCP(co3);
  float sum0 = 0.f, sum1 = 0.f, sum2 = 0.f, sum3 = 0.f;
  for (int kt = 0; kt < NKT; ++kt) {
    const int cur = kt & 1;
    __syncthreads();                       // sK[cur] + cn* resident
    if (kt + 1 < NKT) {
      if (wid < 8) DMA_K(cur ^ 1, kt + 1);
    }
    float b0 = cn0, b1 = cn1, b2 = cn2, b3 = cn3;
    co0 += KB; co1 += KB; co2 += KB; co3 += KB;
    if (kt + 1 < NKT) { cn0 = LDCP(co0); cn1 = LDCP(co1); cn2 = LDCP(co2); cn3 = LDCP(co3); }
    f32x4 acc = {0.f, 0.f, 0.f, 0.f};
    QKSTEP(0, qf0) QKSTEP(1, qf1) QKSTEP(2, qf2) QKSTEP(3, qf3)
    sum0 += __expf(acc[0] * SCALE + b0);
    sum1 += __expf(acc[1] * SCALE + b1);
    sum2 += __expf(acc[2] * SCALE + b2);
    sum3 += __expf(acc[3] * SCALE + b3);
  }

  #pragma unroll
  for (int m = 1; m < 16; m <<= 1) {
    sum0 += __shfl_xor(sum0, m, 64);
    sum1 += __shfl_xor(sum1, m, 64);
    sum2 += __shfl_xor(sum2, m, 64);
    sum3 += __shfl_xor(sum3, m, 64);
  }
  __syncthreads();
  if (l15 == 0) {
    sRedf[(row0 + 0) * 2 + wc] = sum0;
    sRedf[(row0 + 1) * 2 + wc] = sum1;
    sRedf[(row0 + 2) * 2 + wc] = sum2;
    sRedf[(row0 + 3) * 2 + wc] = sum3;
  }
  __syncthreads();
  if (tid < QB) sInvf[tid] = 1.0f / (sRedf[tid * 2] + sRedf[tid * 2 + 1]);
  __syncthreads();
  const float inv0 = sInvf[row0 + 0], inv1 = sInvf[row0 + 1],
              inv2 = sInvf[row0 + 2], inv3 = sInvf[row0 + 3];

  // =================== PASS B: attn_p + O ===================
  co0 = (row0 + 0) * LL + keyloc;
  co1 = co0 + LL; co2 = co1 + LL; co3 = co2 + LL;
  __syncthreads();   // all sInv reads done before sP reuse
  if (wid < 8) DMA_K(0, 0); else DMA_V(0, 0);
  cn0 = LDCP(co0); cn1 = LDCP(co1); cn2 = LDCP(co2); cn3 = LDCP(co3);
  f32x4 o0 = {0,0,0,0}, o1 = {0,0,0,0}, o2 = {0,0,0,0}, o3 = {0,0,0,0};
  for (int kt = 0; kt < NKT; ++kt) {
    const int cur = kt & 1;
    __syncthreads();                       // sK/sVt[cur] + cn* resident; sP free
    if (kt + 1 < NKT) {
      if (wid < 8) DMA_K(cur ^ 1, kt + 1); else DMA_V(cur ^ 1, kt + 1);
    }
    float b0 = cn0, b1 = cn1, b2 = cn2, b3 = cn3;
    co0 += KB; co1 += KB; co2 += KB; co3 += KB;
    if (kt + 1 < NKT) { cn0 = LDCP(co0); cn1 = LDCP(co1); cn2 = LDCP(co2); cn3 = LDCP(co3); }
    f32x4 acc = {0.f, 0.f, 0.f, 0.f};
    QKSTEP(0, qf0) QKSTEP(1, qf1) QKSTEP(2, qf2) QKSTEP(3, qf3)
    float e0 = __expf(acc[0] * SCALE + b0) * inv0;
    float e1 = __expf(acc[1] * SCALE + b1) * inv1;
    float e2 = __expf(acc[2] * SCALE + b2) * inv2;
    float e3 = __expf(acc[3] * SCALE + b3) * inv3;
    const int keyg = kt * KB + keyloc;
    __builtin_nontemporal_store(e0, &oP[(size_t)(row0 + 0) * LL + keyg]);
    __builtin_nontemporal_store(e1, &oP[(size_t)(row0 + 1) * LL + keyg]);
    __builtin_nontemporal_store(e2, &oP[(size_t)(row0 + 2) * LL + keyg]);
    __builtin_nontemporal_store(e3, &oP[(size_t)(row0 + 3) * LL + keyg]);
    sP[(row0 + 0) * KB + (keyloc ^ (slotRC(row0 + 0) << 3))] = f2bf(e0);
    sP[(row0 + 1) * KB + (keyloc ^ (slotRC(row0 + 1) << 3))] = f2bf(e1);
    sP[(row0 + 2) * KB + (keyloc ^ (slotRC(row0 + 2) << 3))] = f2bf(e2);
    sP[(row0 + 3) * KB + (keyloc ^ (slotRC(row0 + 3) << 3))] = f2bf(e3);
    // mid barrier: LDS visibility only — DMA + cpm prefetch stay in flight
    asm volatile("s_waitcnt lgkmcnt(0)\n\ts_barrier" ::: "memory");
    bf16x8 aP = *(const bf16x8*)&sP[qrow * KB + ((l4 * 8) ^ (slotRC(qrow) << 3))];
    #define PVSTEP(DT, OO) { \
      int dcol = wc * 64 + (DT) * 16 + l15; \
      bf16x8 bV = *(const bf16x8*)&sVt[cur][(l4 * 128 + dcol) * 8]; \
      OO = __builtin_amdgcn_mfma_f32_16x16x32_bf16(aP, bV, OO, 0, 0, 0); }
    PVSTEP(0, o0) PVSTEP(1, o1) PVSTEP(2, o2) PVSTEP(3, o3)
    #undef PVSTEP
  }

  // ---- store attention (non-temporal) ----
  #pragma unroll
  for (int r = 0; r < 4; ++r) {
    float* dst = oA + (size_t)(row0 + r) * DD + wc * 64 + l15;
    __builtin_nontemporal_store(o0[r], dst);
    __builtin_nontemporal_store(o1[r], dst + 16);
    __builtin_nontemporal_store(o2[r], dst + 32);
    __builtin_nontemporal_store(o3[r], dst + 48);
  }
}

extern "C" void kernel_launch(void* const* d_in, const int* in_sizes, int n_in,
                              void* d_out, int out_size, void* d_ws, size_t ws_size,
                              hipStream_t stream) {
  const float* q = (const float*)d_in[0];
  const float* k = (const float*)d_in[1];
  const float* v = (const float*)d_in[2];
  const int* mask = (const int*)d_in[3];
  const float* probs = (const float*)d_in[4];
  const float* alpha = (const float*)d_in[5];
  float* outA = (float*)d_out;
  float* outP = outA + (size_t)BB * HH * LL * DD;
  unsigned short* kbT = (unsigned short*)d_ws;
  unsigned short* vtT = kbT + (size_t)32 * 64 * 4096;
  float* cpm = (float*)(vtT + (size_t)32 * 64 * 4096);
  hipLaunchKernelGGL(prep_kernel, dim3(32 * 64), dim3(256), 0, stream,
                     k, v, mask, probs, alpha, kbT, vtT, cpm);
  hipLaunchKernelGGL(attn_kernel, dim3(BB * HH * (LL / QB)), dim3(1024), 0, stream,
                     q, kbT, vtT, cpm, outA, outP);
}

// Round 11
// 368.945 us; speedup vs baseline: 1.9141x; 1.4024x over previous
//
#include <hip/hip_runtime.h>

constexpr int BB = 2, HH = 16, LL = 2048, DD = 128;
constexpr int QB = 64, KB = 32, NKT = LL / KB;   // 64 k-tiles
constexpr float SCALE = 0.08838834764831845f;    // 1/sqrt(128)

typedef __attribute__((ext_vector_type(8))) short bf16x8;
typedef __attribute__((ext_vector_type(8))) unsigned short u16x8;
typedef __attribute__((ext_vector_type(4))) float f32x4;

static __device__ __forceinline__ unsigned short f2bf(float f) {
  unsigned int u = __builtin_bit_cast(unsigned int, f);
  u += 0x7fffu + ((u >> 16) & 1u);   // RNE
  return (unsigned short)(u >> 16);
}
static __device__ __forceinline__ float bf2f(unsigned short h) {
  return __builtin_bit_cast(float, (unsigned int)h << 16);
}
static __device__ __forceinline__ int slotRC(int r) { return ((r >> 1) ^ (r >> 3)) & 3; }

#define GLD16(gsrc, ldst) __builtin_amdgcn_global_load_lds( \
    (const __attribute__((address_space(1))) void*)(gsrc), \
    (__attribute__((address_space(3))) void*)(ldst), 16, 0, 0)

// ---------------- prep ----------------
//   kbT tile [16 dslots][32 keys][8 d]  (bf16)  -> linear-DMA, 2-way LDS reads
//   vtT tile [4 kc][128 d][8 keys]      (bf16)  -> linear-DMA, 2-way LDS reads
//   cpmT[b][key][qrow] = bf16( mask ? probs*alpha : -1e30 )  TRANSPOSED:
//     lane reads 4 consecutive qrows = one 8B load; WG consumes full 128B lines
__global__ __launch_bounds__(256)
void prep_kernel(const float* __restrict__ k, const float* __restrict__ v,
                 const int* __restrict__ mask, const float* __restrict__ probs,
                 const float* __restrict__ alphap,
                 unsigned short* __restrict__ kbT, unsigned short* __restrict__ vtT,
                 unsigned short* __restrict__ cpmT)
{
  __shared__ unsigned short sT[128 * 40];   // V^T tile, 80 B rows
  const int bid = blockIdx.x;
  const int bh = bid >> 6, kt = bid & 63;
  const int t = threadIdx.x;
  const float alpha = alphap[0];
  const size_t tileBase = (size_t)bid * 4096;   // bid == bh*64 + kt
  const float* kg = k + ((size_t)bh * LL + kt * 32) * DD;
  const float* vg = v + ((size_t)bh * LL + kt * 32) * DD;

  // K -> 16B-block-transposed tile
  #pragma unroll
  for (int s = t; s < 512; s += 256) {
    int dsl = s >> 5, key = s & 31;
    const float* src = kg + key * DD + dsl * 8;
    float4 a = *(const float4*)src;
    float4 c = *(const float4*)(src + 4);
    u16x8 w;
    w[0] = f2bf(a.x); w[1] = f2bf(a.y); w[2] = f2bf(a.z); w[3] = f2bf(a.w);
    w[4] = f2bf(c.x); w[5] = f2bf(c.y); w[6] = f2bf(c.z); w[7] = f2bf(c.w);
    *(u16x8*)(kbT + tileBase + (size_t)s * 8) = w;
  }
  // V -> sT (transpose)
  #pragma unroll
  for (int i = 0; i < 4; ++i) {
    int idx = i * 256 + t;
    int key = idx >> 5, d4 = (idx & 31) * 4;
    float4 x = ((const float4*)vg)[idx];
    sT[(d4 + 0) * 40 + key] = f2bf(x.x);
    sT[(d4 + 1) * 40 + key] = f2bf(x.y);
    sT[(d4 + 2) * 40 + key] = f2bf(x.z);
    sT[(d4 + 3) * 40 + key] = f2bf(x.w);
  }
  // cpmT: register-only 4x4 micro-transpose, 64x64 tile per block
  {
    const int b = bid >> 10, rem = bid & 1023;
    const int tq = rem >> 5, tk = rem & 31;
    const int q0t = tq * 64 + (t >> 4) * 4;
    const int k0t = tk * 64 + (t & 15) * 4;
    const float* pb = probs + (size_t)b * LL * LL;
    const int* mb = mask + (size_t)b * LL * LL;
    float4 r0 = *(const float4*)(pb + (size_t)(q0t + 0) * LL + k0t);
    float4 r1 = *(const float4*)(pb + (size_t)(q0t + 1) * LL + k0t);
    float4 r2 = *(const float4*)(pb + (size_t)(q0t + 2) * LL + k0t);
    float4 r3 = *(const float4*)(pb + (size_t)(q0t + 3) * LL + k0t);
    int4 m0 = *(const int4*)(mb + (size_t)(q0t + 0) * LL + k0t);
    int4 m1 = *(const int4*)(mb + (size_t)(q0t + 1) * LL + k0t);
    int4 m2 = *(const int4*)(mb + (size_t)(q0t + 2) * LL + k0t);
    int4 m3 = *(const int4*)(mb + (size_t)(q0t + 3) * LL + k0t);
    unsigned short* ct = cpmT + (size_t)b * LL * LL + q0t;
    #define CW(J) { \
      ushort4 o; \
      o.x = f2bf(m0.J ? r0.J * alpha : -1e30f); \
      o.y = f2bf(m1.J ? r1.J * alpha : -1e30f); \
      o.z = f2bf(m2.J ? r2.J * alpha : -1e30f); \
      o.w = f2bf(m3.J ? r3.J * alpha : -1e30f); \
      *(ushort4*)(ct + (size_t)(k0t + jj) * LL) = o; }
    { int jj = 0; CW(x) } { int jj = 1; CW(y) } { int jj = 2; CW(z) } { int jj = 3; CW(w) }
    #undef CW
  }
  __syncthreads();
  // sT -> vtT tile [kc][d][8]
  #pragma unroll
  for (int s = t; s < 512; s += 256) {
    int kc = s >> 7, d = s & 127;
    u16x8 w = *(const u16x8*)&sT[d * 40 + kc * 8];
    *(u16x8*)(vtT + tileBase + (size_t)s * 8) = w;
  }
}

// ---------------- main fused attention (QB=64, 512 threads = 8 waves) ----------------
__global__ __launch_bounds__(512, 8)
void attn_kernel(const float* __restrict__ q, const unsigned short* __restrict__ kbT,
                 const unsigned short* __restrict__ vtT, const unsigned short* __restrict__ cpmT,
                 float* __restrict__ outA, float* __restrict__ outP)
{
  __shared__ unsigned short sK[2][4096];    // 16 KB dbuf, tile [dslot][key][8]
  __shared__ unsigned short sVt[2][4096];   // 16 KB dbuf, tile [kc][d][8]
  __shared__ unsigned short sP[2048];       // 4 KB P tile (aliases sRed/sInv)
  float* sRedf = (float*)sP;
  float* sInvf = sRedf + 128;

  const int tid = threadIdx.x;
  const int lane = tid & 63;
  const int wid = tid >> 6;
  const int l15 = lane & 15;
  const int l4 = lane >> 4;
  const int wr = wid >> 1, wc = wid & 1;

  // XCD-chunked swizzle: XCD x (= bid%8) owns work [x*128, x*128+128)
  // bh-major decode -> each XCD touches 4 bh
  const int bid = blockIdx.x;
  const int work = ((bid & 7) << 7) | (bid >> 3);
  const int bh = work >> 5;     // 0..31
  const int qt = work & 31;     // 0..31
  const int b = bh >> 4;
  const int q0 = qt * QB;

  const unsigned short* kbh = kbT + (size_t)bh * 64 * 4096;
  const unsigned short* vbh = vtT + (size_t)bh * 64 * 4096;
  const unsigned short* cgT = cpmT + (size_t)b * LL * LL + q0;   // + key*LL + row
  float* oA = outA + (size_t)(bh * LL + q0) * DD;
  float* oP = outP + (size_t)bh * LL * LL + (size_t)q0 * LL;

  const int qrow = wr * 16 + l15;     // wave's q-row for A-frags
  const int keyloc = wc * 16 + l15;   // wave's key column (QK B-frag)
  const int row0 = wr * 16 + l4 * 4;  // acc row base

  // ---- Q fragments straight from global (one-time) ----
  bf16x8 qf0, qf1, qf2, qf3;
  {
    const float* qs = q + (size_t)(bh * LL + q0 + qrow) * DD + l4 * 8;
    #define LQ(FR, KC) { \
      float4 a = *(const float4*)(qs + (KC) * 32); \
      float4 c = *(const float4*)(qs + (KC) * 32 + 4); \
      FR[0]=(short)f2bf(a.x); FR[1]=(short)f2bf(a.y); FR[2]=(short)f2bf(a.z); FR[3]=(short)f2bf(a.w); \
      FR[4]=(short)f2bf(c.x); FR[5]=(short)f2bf(c.y); FR[6]=(short)f2bf(c.z); FR[7]=(short)f2bf(c.w); }
    LQ(qf0, 0) LQ(qf1, 1) LQ(qf2, 2) LQ(qf3, 3)
    #undef LQ
  }

  const int ldsW = wid << 9;   // u16 elements: 1 KB per wave
  #define DMA_K(BUF, KT) GLD16(kbh + (size_t)(KT) * 4096 + tid * 8, &sK[BUF][ldsW])
  #define DMA_V(BUF, KT) GLD16(vbh + (size_t)(KT) * 4096 + tid * 8, &sVt[BUF][ldsW])

  #define QKSTEP(KC, QF) { \
    bf16x8 bK = *(const bf16x8*)&sK[cur][(((KC) * 4 + l4) * 32 + keyloc) * 8]; \
    acc = __builtin_amdgcn_mfma_f32_16x16x32_bf16(QF, bK, acc, 0, 0, 0); }

  // one 8B load = biases for rows row0..row0+3 at this lane's key column
  #define LDCP4(KEYG) (*(const ushort4*)(cgT + (size_t)(KEYG) * LL + row0))

  // =================== PASS A: rowsums ===================
  DMA_K(0, 0);
  ushort4 cn = LDCP4(keyloc);
  float sum0 = 0.f, sum1 = 0.f, sum2 = 0.f, sum3 = 0.f;
  for (int kt = 0; kt < NKT; ++kt) {
    const int cur = kt & 1;
    __syncthreads();                       // sK[cur] + cn resident
    if (kt + 1 < NKT) DMA_K(cur ^ 1, kt + 1);
    ushort4 bq = cn;
    if (kt + 1 < NKT) cn = LDCP4((kt + 1) * KB + keyloc);
    f32x4 acc = {0.f, 0.f, 0.f, 0.f};
    QKSTEP(0, qf0) QKSTEP(1, qf1) QKSTEP(2, qf2) QKSTEP(3, qf3)
    sum0 += __expf(acc[0] * SCALE + bf2f(bq.x));
    sum1 += __expf(acc[1] * SCALE + bf2f(bq.y));
    sum2 += __expf(acc[2] * SCALE + bf2f(bq.z));
    sum3 += __expf(acc[3] * SCALE + bf2f(bq.w));
  }

  #pragma unroll
  for (int m = 1; m < 16; m <<= 1) {
    sum0 += __shfl_xor(sum0, m, 64);
    sum1 += __shfl_xor(sum1, m, 64);
    sum2 += __shfl_xor(sum2, m, 64);
    sum3 += __shfl_xor(sum3, m, 64);
  }
  __syncthreads();
  if (l15 == 0) {
    sRedf[(row0 + 0) * 2 + wc] = sum0;
    sRedf[(row0 + 1) * 2 + wc] = sum1;
    sRedf[(row0 + 2) * 2 + wc] = sum2;
    sRedf[(row0 + 3) * 2 + wc] = sum3;
  }
  __syncthreads();
  if (tid < QB) sInvf[tid] = 1.0f / (sRedf[tid * 2] + sRedf[tid * 2 + 1]);
  __syncthreads();
  const float inv0 = sInvf[row0 + 0], inv1 = sInvf[row0 + 1],
              inv2 = sInvf[row0 + 2], inv3 = sInvf[row0 + 3];

  // =================== PASS B: attn_p + O ===================
  __syncthreads();   // sInv reads done before sP reuse
  DMA_K(0, 0); DMA_V(0, 0);
  cn = LDCP4(keyloc);
  f32x4 o0 = {0,0,0,0}, o1 = {0,0,0,0}, o2 = {0,0,0,0}, o3 = {0,0,0,0};
  for (int kt = 0; kt < NKT; ++kt) {
    const int cur = kt & 1;
    __syncthreads();                       // sK/sVt[cur] + cn resident; sP free
    if (kt + 1 < NKT) { DMA_K(cur ^ 1, kt + 1); DMA_V(cur ^ 1, kt + 1); }
    ushort4 bq = cn;
    if (kt + 1 < NKT) cn = LDCP4((kt + 1) * KB + keyloc);
    f32x4 acc = {0.f, 0.f, 0.f, 0.f};
    QKSTEP(0, qf0) QKSTEP(1, qf1) QKSTEP(2, qf2) QKSTEP(3, qf3)
    float e0 = __expf(acc[0] * SCALE + bf2f(bq.x)) * inv0;
    float e1 = __expf(acc[1] * SCALE + bf2f(bq.y)) * inv1;
    float e2 = __expf(acc[2] * SCALE + bf2f(bq.z)) * inv2;
    float e3 = __expf(acc[3] * SCALE + bf2f(bq.w)) * inv3;
    const int keyg = kt * KB + keyloc;
    // non-temporal: keep the 537 MB attn_p stream from evicting L2/L3 reads
    __builtin_nontemporal_store(e0, &oP[(size_t)(row0 + 0) * LL + keyg]);
    __builtin_nontemporal_store(e1, &oP[(size_t)(row0 + 1) * LL + keyg]);
    __builtin_nontemporal_store(e2, &oP[(size_t)(row0 + 2) * LL + keyg]);
    __builtin_nontemporal_store(e3, &oP[(size_t)(row0 + 3) * LL + keyg]);
    sP[(row0 + 0) * KB + (keyloc ^ (slotRC(row0 + 0) << 3))] = f2bf(e0);
    sP[(row0 + 1) * KB + (keyloc ^ (slotRC(row0 + 1) << 3))] = f2bf(e1);
    sP[(row0 + 2) * KB + (keyloc ^ (slotRC(row0 + 2) << 3))] = f2bf(e2);
    sP[(row0 + 3) * KB + (keyloc ^ (slotRC(row0 + 3) << 3))] = f2bf(e3);
    // mid barrier: LDS visibility only — DMA + bias prefetch stay in flight
    asm volatile("s_waitcnt lgkmcnt(0)\n\ts_barrier" ::: "memory");
    bf16x8 aP = *(const bf16x8*)&sP[qrow * KB + ((l4 * 8) ^ (slotRC(qrow) << 3))];
    #define PVSTEP(DT, OO) { \
      int dcol = wc * 64 + (DT) * 16 + l15; \
      bf16x8 bV = *(const bf16x8*)&sVt[cur][(l4 * 128 + dcol) * 8]; \
      OO = __builtin_amdgcn_mfma_f32_16x16x32_bf16(aP, bV, OO, 0, 0, 0); }
    PVSTEP(0, o0) PVSTEP(1, o1) PVSTEP(2, o2) PVSTEP(3, o3)
    #undef PVSTEP
  }

  // ---- store attention (non-temporal) ----
  #pragma unroll
  for (int r = 0; r < 4; ++r) {
    float* dst = oA + (size_t)(row0 + r) * DD + wc * 64 + l15;
    __builtin_nontemporal_store(o0[r], dst);
    __builtin_nontemporal_store(o1[r], dst + 16);
    __builtin_nontemporal_store(o2[r], dst + 32);
    __builtin_nontemporal_store(o3[r], dst + 48);
  }
}

extern "C" void kernel_launch(void* const* d_in, const int* in_sizes, int n_in,
                              void* d_out, int out_size, void* d_ws, size_t ws_size,
                              hipStream_t stream) {
  const float* q = (const float*)d_in[0];
  const float* k = (const float*)d_in[1];
  const float* v = (const float*)d_in[2];
  const int* mask = (const int*)d_in[3];
  const float* probs = (const float*)d_in[4];
  const float* alpha = (const float*)d_in[5];
  float* outA = (float*)d_out;
  float* outP = outA + (size_t)BB * HH * LL * DD;
  unsigned short* kbT = (unsigned short*)d_ws;
  unsigned short* vtT = kbT + (size_t)32 * 64 * 4096;
  unsigned short* cpmT = vtT + (size_t)32 * 64 * 4096;
  hipLaunchKernelGGL(prep_kernel, dim3(32 * 64), dim3(256), 0, stream,
                     k, v, mask, probs, alpha, kbT, vtT, cpmT);
  hipLaunchKernelGGL(attn_kernel, dim3(BB * HH * (LL / QB)), dim3(512), 0, stream,
                     q, kbT, vtT, cpmT, outA, outP);
}

// Round 12
// 286.424 us; speedup vs baseline: 2.4655x; 1.2881x over previous
//
#include <hip/hip_runtime.h>

constexpr int BB = 2, HH = 16, LL = 2048, DD = 128;
constexpr int QB = 64, KB = 32, NKT = LL / KB;   // 64 k-tiles
constexpr float SCALE = 0.08838834764831845f;    // 1/sqrt(128)

typedef __attribute__((ext_vector_type(8))) short bf16x8;
typedef __attribute__((ext_vector_type(8))) unsigned short u16x8;
typedef __attribute__((ext_vector_type(4))) float f32x4;
typedef __attribute__((ext_vector_type(4))) int i32x4;

static __device__ __forceinline__ unsigned short f2bf(float f) {
  unsigned int u = __builtin_bit_cast(unsigned int, f);
  u += 0x7fffu + ((u >> 16) & 1u);   // RNE
  return (unsigned short)(u >> 16);
}
static __device__ __forceinline__ float bf2f(unsigned short h) {
  return __builtin_bit_cast(float, (unsigned int)h << 16);
}

#define GLD16(gsrc, ldst) __builtin_amdgcn_global_load_lds( \
    (const __attribute__((address_space(1))) void*)(gsrc), \
    (__attribute__((address_space(3))) void*)(ldst), 16, 0, 0)

// ---------------- prep ----------------
//   kbT tile [16 dslots][32 keys][8 d]  (bf16)  -> linear-DMA
//   vtT tile [4 kc][128 d][8 keys]      (bf16)  -> linear-DMA
//   cpw = bf16( mask ? probs*alpha : -1e30 )  flat [q][key] (ushort4-coalesced reads)
__global__ __launch_bounds__(256)
void prep_kernel(const float* __restrict__ k, const float* __restrict__ v,
                 const int* __restrict__ mask, const float* __restrict__ probs,
                 const float* __restrict__ alphap,
                 unsigned short* __restrict__ kbT, unsigned short* __restrict__ vtT,
                 unsigned short* __restrict__ cpw)
{
  __shared__ unsigned short sT[128 * 40];   // V^T tile, 80 B rows
  const int bid = blockIdx.x;
  const int bh = bid >> 6, kt = bid & 63;
  const int t = threadIdx.x;
  const float alpha = alphap[0];
  const size_t tileBase = (size_t)bid * 4096;   // bid == bh*64 + kt
  const float* kg = k + ((size_t)bh * LL + kt * 32) * DD;
  const float* vg = v + ((size_t)bh * LL + kt * 32) * DD;

  // K -> 16B-block-transposed tile
  #pragma unroll
  for (int s = t; s < 512; s += 256) {
    int dsl = s >> 5, key = s & 31;
    const float* src = kg + key * DD + dsl * 8;
    float4 a = *(const float4*)src;
    float4 c = *(const float4*)(src + 4);
    u16x8 w;
    w[0] = f2bf(a.x); w[1] = f2bf(a.y); w[2] = f2bf(a.z); w[3] = f2bf(a.w);
    w[4] = f2bf(c.x); w[5] = f2bf(c.y); w[6] = f2bf(c.z); w[7] = f2bf(c.w);
    *(u16x8*)(kbT + tileBase + (size_t)s * 8) = w;
  }
  // V -> sT (transpose)
  #pragma unroll
  for (int i = 0; i < 4; ++i) {
    int idx = i * 256 + t;
    int key = idx >> 5, d4 = (idx & 31) * 4;
    float4 x = ((const float4*)vg)[idx];
    sT[(d4 + 0) * 40 + key] = f2bf(x.x);
    sT[(d4 + 1) * 40 + key] = f2bf(x.y);
    sT[(d4 + 2) * 40 + key] = f2bf(x.z);
    sT[(d4 + 3) * 40 + key] = f2bf(x.w);
  }
  // cpw (flat, bf16)
  {
    const float4* ps = (const float4*)probs;
    const int4* ms = (const int4*)mask;
    ushort4* cs = (ushort4*)cpw;
    size_t base = (size_t)bid * 1024;
    #pragma unroll
    for (int i = 0; i < 4; ++i) {
      size_t idx = base + i * 256 + t;
      float4 p = ps[idx];
      int4 m = ms[idx];
      ushort4 o;
      o.x = f2bf(m.x ? p.x * alpha : -1e30f);
      o.y = f2bf(m.y ? p.y * alpha : -1e30f);
      o.z = f2bf(m.z ? p.z * alpha : -1e30f);
      o.w = f2bf(m.w ? p.w * alpha : -1e30f);
      cs[idx] = o;
    }
  }
  __syncthreads();
  // sT -> vtT tile [kc][d][8]
  #pragma unroll
  for (int s = t; s < 512; s += 256) {
    int kc = s >> 7, d = s & 127;
    u16x8 w = *(const u16x8*)&sT[d * 40 + kc * 8];
    *(u16x8*)(vtT + tileBase + (size_t)s * 8) = w;
  }
}

// ---------------- main fused attention ----------------
// 256 threads = 4 waves, QB=64. Swapped QK: mfma(K, Q) => lane holds P for
// ONE q-row (l15) x 8 keys. Rowsum is in-register; P->PV frag via cvt_pk+shfl.
// ONE barrier per k-tile; no sP/sInv LDS.
__global__ __launch_bounds__(256, 4)
void attn_kernel(const float* __restrict__ q, const unsigned short* __restrict__ kbT,
                 const unsigned short* __restrict__ vtT, const unsigned short* __restrict__ cpw,
                 float* __restrict__ outA, float* __restrict__ outP)
{
  __shared__ unsigned short sK[2][4096];    // 16 KB dbuf, tile [dslot][key][8]
  __shared__ unsigned short sVt[2][4096];   // 16 KB dbuf, tile [kc][d][8]

  const int tid = threadIdx.x;
  const int lane = tid & 63;
  const int wid = tid >> 6;     // 0..3, wave owns rows wid*16..+16
  const int l15 = lane & 15;
  const int l4 = lane >> 4;

  // XCD-chunked swizzle (bh-major): each XCD touches 4 bh
  const int bid = blockIdx.x;
  const int work = ((bid & 7) << 7) | (bid >> 3);
  const int bh = work >> 5;     // 0..31
  const int qt = work & 31;     // 0..31
  const int b = bh >> 4;
  const int q0 = qt * QB;
  const int row16 = wid << 4;

  const unsigned short* kbh = kbT + (size_t)bh * 64 * 4096;
  const unsigned short* vbh = vtT + (size_t)bh * 64 * 4096;
  const unsigned short* cgrow = cpw + (size_t)b * LL * LL + (size_t)(q0 + row16 + l15) * LL;
  float* oA = outA + (size_t)(bh * LL + q0) * DD;
  float* oPr = outP + (size_t)bh * LL * LL + (size_t)(q0 + row16 + l15) * LL;

  // ---- Q fragments (this lane's q-row = l15 within wave block) ----
  bf16x8 qf0, qf1, qf2, qf3;
  {
    const float* qs = q + (size_t)(bh * LL + q0 + row16 + l15) * DD + l4 * 8;
    #define LQ(FR, KC) { \
      float4 a = *(const float4*)(qs + (KC) * 32); \
      float4 c = *(const float4*)(qs + (KC) * 32 + 4); \
      FR[0]=(short)f2bf(a.x); FR[1]=(short)f2bf(a.y); FR[2]=(short)f2bf(a.z); FR[3]=(short)f2bf(a.w); \
      FR[4]=(short)f2bf(c.x); FR[5]=(short)f2bf(c.y); FR[6]=(short)f2bf(c.z); FR[7]=(short)f2bf(c.w); }
    LQ(qf0, 0) LQ(qf1, 1) LQ(qf2, 2) LQ(qf3, 3)
    #undef LQ
  }

  // DMA: 256 threads, 2 x GLD16 per 8 KB tile (linear s = issue*256 + tid)
  #define DMA_K(BUF, KT) do { \
    GLD16(kbh + (size_t)(KT) * 4096 + tid * 8,         &sK[BUF][wid << 9]); \
    GLD16(kbh + (size_t)(KT) * 4096 + (256 + tid) * 8, &sK[BUF][2048 + (wid << 9)]); } while (0)
  #define DMA_V(BUF, KT) do { \
    GLD16(vbh + (size_t)(KT) * 4096 + tid * 8,         &sVt[BUF][wid << 9]); \
    GLD16(vbh + (size_t)(KT) * 4096 + (256 + tid) * 8, &sVt[BUF][2048 + (wid << 9)]); } while (0)

  // Swapped QK: A = K[16 key][32 d] (key = l15 / +16), B = Q (qf), D[key][q=l15]
  #define QKS(KC, QF) { \
    bf16x8 k0 = *(const bf16x8*)&sK[cur][(((KC) * 4 + l4) * 32 + l15) * 8]; \
    a0 = __builtin_amdgcn_mfma_f32_16x16x32_bf16(k0, QF, a0, 0, 0, 0); \
    bf16x8 k1 = *(const bf16x8*)&sK[cur][(((KC) * 4 + l4) * 32 + 16 + l15) * 8]; \
    a1 = __builtin_amdgcn_mfma_f32_16x16x32_bf16(k1, QF, a1, 0, 0, 0); }

  // =================== PASS A: rowsums ===================
  DMA_K(0, 0);
  ushort4 cn0 = *(const ushort4*)(cgrow + (l4 << 2));
  ushort4 cn1 = *(const ushort4*)(cgrow + 16 + (l4 << 2));
  float sum = 0.f;
  for (int kt = 0; kt < NKT; ++kt) {
    const int cur = kt & 1;
    __syncthreads();                       // sK[cur] resident
    if (kt + 1 < NKT) DMA_K(cur ^ 1, kt + 1);
    ushort4 b0 = cn0, b1 = cn1;
    if (kt + 1 < NKT) {
      cn0 = *(const ushort4*)(cgrow + (kt + 1) * 32 + (l4 << 2));
      cn1 = *(const ushort4*)(cgrow + (kt + 1) * 32 + 16 + (l4 << 2));
    }
    f32x4 a0 = {0.f,0.f,0.f,0.f}, a1 = {0.f,0.f,0.f,0.f};
    QKS(0, qf0) QKS(1, qf1) QKS(2, qf2) QKS(3, qf3)
    sum += __expf(a0[0] * SCALE + bf2f(b0.x));
    sum += __expf(a0[1] * SCALE + bf2f(b0.y));
    sum += __expf(a0[2] * SCALE + bf2f(b0.z));
    sum += __expf(a0[3] * SCALE + bf2f(b0.w));
    sum += __expf(a1[0] * SCALE + bf2f(b1.x));
    sum += __expf(a1[1] * SCALE + bf2f(b1.y));
    sum += __expf(a1[2] * SCALE + bf2f(b1.z));
    sum += __expf(a1[3] * SCALE + bf2f(b1.w));
  }
  // reduce over the 4 l4-copies of this q-row (lanes l15, +16, +32, +48)
  sum += __shfl_xor(sum, 16, 64);
  sum += __shfl_xor(sum, 32, 64);
  const float inv = 1.0f / sum;

  // =================== PASS B: attn_p + O ===================
  __syncthreads();   // all pass-A LDS reads done
  DMA_K(0, 0); DMA_V(0, 0);
  cn0 = *(const ushort4*)(cgrow + (l4 << 2));
  cn1 = *(const ushort4*)(cgrow + 16 + (l4 << 2));
  f32x4 oacc[8];
  #pragma unroll
  for (int dt = 0; dt < 8; ++dt) oacc[dt] = (f32x4){0.f,0.f,0.f,0.f};

  const int srcA = l15 + (((l4 << 1) + 0) & 3) * 16;
  const int srcB = l15 + (((l4 << 1) + 1) & 3) * 16;
  const bool hiTile = (l4 >= 2);

  for (int kt = 0; kt < NKT; ++kt) {
    const int cur = kt & 1;
    __syncthreads();                       // sK/sVt[cur] resident
    if (kt + 1 < NKT) { DMA_K(cur ^ 1, kt + 1); DMA_V(cur ^ 1, kt + 1); }
    ushort4 b0 = cn0, b1 = cn1;
    if (kt + 1 < NKT) {
      cn0 = *(const ushort4*)(cgrow + (kt + 1) * 32 + (l4 << 2));
      cn1 = *(const ushort4*)(cgrow + (kt + 1) * 32 + 16 + (l4 << 2));
    }
    f32x4 a0 = {0.f,0.f,0.f,0.f}, a1 = {0.f,0.f,0.f,0.f};
    QKS(0, qf0) QKS(1, qf1) QKS(2, qf2) QKS(3, qf3)

    // normalized p for (q = l15, keys kt*32 + l4*4..+4 and +16)
    f32x4 p0, p1;
    p0[0] = __expf(a0[0] * SCALE + bf2f(b0.x)) * inv;
    p0[1] = __expf(a0[1] * SCALE + bf2f(b0.y)) * inv;
    p0[2] = __expf(a0[2] * SCALE + bf2f(b0.z)) * inv;
    p0[3] = __expf(a0[3] * SCALE + bf2f(b0.w)) * inv;
    p1[0] = __expf(a1[0] * SCALE + bf2f(b1.x)) * inv;
    p1[1] = __expf(a1[1] * SCALE + bf2f(b1.y)) * inv;
    p1[2] = __expf(a1[2] * SCALE + bf2f(b1.z)) * inv;
    p1[3] = __expf(a1[3] * SCALE + bf2f(b1.w)) * inv;

    // attn_p: two float4 nt-stores (row l15, 4 consecutive keys each)
    __builtin_nontemporal_store(p0, (f32x4*)(oPr + kt * 32 + (l4 << 2)));
    __builtin_nontemporal_store(p1, (f32x4*)(oPr + kt * 32 + 16 + (l4 << 2)));

    // pack p -> bf16 dwords, redistribute across l4 groups to form PV A-frag:
    // frag element j = P[q=l15][key = l4*8 + j]
    unsigned d00, d01, d10, d11;
    asm("v_cvt_pk_bf16_f32 %0, %1, %2" : "=v"(d00) : "v"(p0[0]), "v"(p0[1]));
    asm("v_cvt_pk_bf16_f32 %0, %1, %2" : "=v"(d01) : "v"(p0[2]), "v"(p0[3]));
    asm("v_cvt_pk_bf16_f32 %0, %1, %2" : "=v"(d10) : "v"(p1[0]), "v"(p1[1]));
    asm("v_cvt_pk_bf16_f32 %0, %1, %2" : "=v"(d11) : "v"(p1[2]), "v"(p1[3]));
    int a00 = __shfl((int)d00, srcA, 64);
    int a01 = __shfl((int)d01, srcA, 64);
    int a02 = __shfl((int)d00, srcB, 64);
    int a03 = __shfl((int)d01, srcB, 64);
    int b00 = __shfl((int)d10, srcA, 64);
    int b01 = __shfl((int)d11, srcA, 64);
    int b02 = __shfl((int)d10, srcB, 64);
    int b03 = __shfl((int)d11, srcB, 64);
    i32x4 fw;
    fw[0] = hiTile ? b00 : a00;
    fw[1] = hiTile ? b01 : a01;
    fw[2] = hiTile ? b02 : a02;
    fw[3] = hiTile ? b03 : a03;
    bf16x8 aP = __builtin_bit_cast(bf16x8, fw);

    // PV: D[q][d], 8 d-chunks of 16
    #pragma unroll
    for (int dt = 0; dt < 8; ++dt) {
      bf16x8 bV = *(const bf16x8*)&sVt[cur][(l4 * 128 + dt * 16 + l15) * 8];
      oacc[dt] = __builtin_amdgcn_mfma_f32_16x16x32_bf16(aP, bV, oacc[dt], 0, 0, 0);
    }
  }

  // ---- store attention (already normalized; PV D rows = l4*4+r) ----
  #pragma unroll
  for (int dt = 0; dt < 8; ++dt) {
    #pragma unroll
    for (int r = 0; r < 4; ++r) {
      __builtin_nontemporal_store(oacc[dt][r],
          oA + (size_t)(row16 + (l4 << 2) + r) * DD + dt * 16 + l15);
    }
  }
}

extern "C" void kernel_launch(void* const* d_in, const int* in_sizes, int n_in,
                              void* d_out, int out_size, void* d_ws, size_t ws_size,
                              hipStream_t stream) {
  const float* q = (const float*)d_in[0];
  const float* k = (const float*)d_in[1];
  const float* v = (const float*)d_in[2];
  const int* mask = (const int*)d_in[3];
  const float* probs = (const float*)d_in[4];
  const float* alpha = (const float*)d_in[5];
  float* outA = (float*)d_out;
  float* outP = outA + (size_t)BB * HH * LL * DD;
  unsigned short* kbT = (unsigned short*)d_ws;
  unsigned short* vtT = kbT + (size_t)32 * 64 * 4096;
  unsigned short* cpw = vtT + (size_t)32 * 64 * 4096;
  hipLaunchKernelGGL(prep_kernel, dim3(32 * 64), dim3(256), 0, stream,
                     k, v, mask, probs, alpha, kbT, vtT, cpw);
  hipLaunchKernelGGL(attn_kernel, dim3(BB * HH * (LL / QB)), dim3(256), 0, stream,
                     q, kbT, vtT, cpw, outA, outP);
}

// Round 13
// 280.321 us; speedup vs baseline: 2.5192x; 1.0218x over previous
//
#include <hip/hip_runtime.h>

constexpr int BB = 2, HH = 16, LL = 2048, DD = 128;
constexpr int QB = 64, KB = 32, NKT = LL / KB;   // 64 k-tiles
constexpr float SCALE = 0.08838834764831845f;    // 1/sqrt(128)

typedef __attribute__((ext_vector_type(8))) short bf16x8;
typedef __attribute__((ext_vector_type(8))) unsigned short u16x8;
typedef __attribute__((ext_vector_type(4))) float f32x4;
typedef __attribute__((ext_vector_type(4))) int i32x4;

static __device__ __forceinline__ unsigned short f2bf(float f) {
  unsigned int u = __builtin_bit_cast(unsigned int, f);
  u += 0x7fffu + ((u >> 16) & 1u);   // RNE
  return (unsigned short)(u >> 16);
}
static __device__ __forceinline__ float bf2f(unsigned short h) {
  return __builtin_bit_cast(float, (unsigned int)h << 16);
}

#define GLD16(gsrc, ldst) __builtin_amdgcn_global_load_lds( \
    (const __attribute__((address_space(1))) void*)(gsrc), \
    (__attribute__((address_space(3))) void*)(ldst), 16, 0, 0)

// ---------------- prep (unchanged from r12) ----------------
__global__ __launch_bounds__(256)
void prep_kernel(const float* __restrict__ k, const float* __restrict__ v,
                 const int* __restrict__ mask, const float* __restrict__ probs,
                 const float* __restrict__ alphap,
                 unsigned short* __restrict__ kbT, unsigned short* __restrict__ vtT,
                 unsigned short* __restrict__ cpw)
{
  __shared__ unsigned short sT[128 * 40];   // V^T tile, 80 B rows
  const int bid = blockIdx.x;
  const int bh = bid >> 6, kt = bid & 63;
  const int t = threadIdx.x;
  const float alpha = alphap[0];
  const size_t tileBase = (size_t)bid * 4096;   // bid == bh*64 + kt
  const float* kg = k + ((size_t)bh * LL + kt * 32) * DD;
  const float* vg = v + ((size_t)bh * LL + kt * 32) * DD;

  #pragma unroll
  for (int s = t; s < 512; s += 256) {
    int dsl = s >> 5, key = s & 31;
    const float* src = kg + key * DD + dsl * 8;
    float4 a = *(const float4*)src;
    float4 c = *(const float4*)(src + 4);
    u16x8 w;
    w[0] = f2bf(a.x); w[1] = f2bf(a.y); w[2] = f2bf(a.z); w[3] = f2bf(a.w);
    w[4] = f2bf(c.x); w[5] = f2bf(c.y); w[6] = f2bf(c.z); w[7] = f2bf(c.w);
    *(u16x8*)(kbT + tileBase + (size_t)s * 8) = w;
  }
  #pragma unroll
  for (int i = 0; i < 4; ++i) {
    int idx = i * 256 + t;
    int key = idx >> 5, d4 = (idx & 31) * 4;
    float4 x = ((const float4*)vg)[idx];
    sT[(d4 + 0) * 40 + key] = f2bf(x.x);
    sT[(d4 + 1) * 40 + key] = f2bf(x.y);
    sT[(d4 + 2) * 40 + key] = f2bf(x.z);
    sT[(d4 + 3) * 40 + key] = f2bf(x.w);
  }
  {
    const float4* ps = (const float4*)probs;
    const int4* ms = (const int4*)mask;
    ushort4* cs = (ushort4*)cpw;
    size_t base = (size_t)bid * 1024;
    #pragma unroll
    for (int i = 0; i < 4; ++i) {
      size_t idx = base + i * 256 + t;
      float4 p = ps[idx];
      int4 m = ms[idx];
      ushort4 o;
      o.x = f2bf(m.x ? p.x * alpha : -1e30f);
      o.y = f2bf(m.y ? p.y * alpha : -1e30f);
      o.z = f2bf(m.z ? p.z * alpha : -1e30f);
      o.w = f2bf(m.w ? p.w * alpha : -1e30f);
      cs[idx] = o;
    }
  }
  __syncthreads();
  #pragma unroll
  for (int s = t; s < 512; s += 256) {
    int kc = s >> 7, d = s & 127;
    u16x8 w = *(const u16x8*)&sT[d * 40 + kc * 8];
    *(u16x8*)(vtT + tileBase + (size_t)s * 8) = w;
  }
}

// ---------------- pass A: rowsums -> invW ----------------
// Only needs sK (16 KB LDS) and ~60 VGPR -> 6 blocks/CU, 24 waves/CU.
__global__ __launch_bounds__(256, 6)
void passA_kernel(const float* __restrict__ q, const unsigned short* __restrict__ kbT,
                  const unsigned short* __restrict__ cpw, float* __restrict__ invW)
{
  __shared__ unsigned short sK[2][4096];

  const int tid = threadIdx.x;
  const int lane = tid & 63;
  const int wid = tid >> 6;
  const int l15 = lane & 15;
  const int l4 = lane >> 4;

  const int bid = blockIdx.x;
  const int work = ((bid & 7) << 7) | (bid >> 3);
  const int bh = work >> 5;
  const int qt = work & 31;
  const int b = bh >> 4;
  const int q0 = qt * QB;
  const int row16 = wid << 4;

  const unsigned short* kbh = kbT + (size_t)bh * 64 * 4096;
  const unsigned short* cgrow = cpw + (size_t)b * LL * LL + (size_t)(q0 + row16 + l15) * LL;

  bf16x8 qf0, qf1, qf2, qf3;
  {
    const float* qs = q + (size_t)(bh * LL + q0 + row16 + l15) * DD + l4 * 8;
    #define LQ(FR, KC) { \
      float4 a = *(const float4*)(qs + (KC) * 32); \
      float4 c = *(const float4*)(qs + (KC) * 32 + 4); \
      FR[0]=(short)f2bf(a.x); FR[1]=(short)f2bf(a.y); FR[2]=(short)f2bf(a.z); FR[3]=(short)f2bf(a.w); \
      FR[4]=(short)f2bf(c.x); FR[5]=(short)f2bf(c.y); FR[6]=(short)f2bf(c.z); FR[7]=(short)f2bf(c.w); }
    LQ(qf0, 0) LQ(qf1, 1) LQ(qf2, 2) LQ(qf3, 3)
    #undef LQ
  }

  #define DMA_K(BUF, KT) do { \
    GLD16(kbh + (size_t)(KT) * 4096 + tid * 8,         &sK[BUF][wid << 9]); \
    GLD16(kbh + (size_t)(KT) * 4096 + (256 + tid) * 8, &sK[BUF][2048 + (wid << 9)]); } while (0)

  #define QKS(KC, QF) { \
    bf16x8 k0 = *(const bf16x8*)&sK[cur][(((KC) * 4 + l4) * 32 + l15) * 8]; \
    a0 = __builtin_amdgcn_mfma_f32_16x16x32_bf16(k0, QF, a0, 0, 0, 0); \
    bf16x8 k1 = *(const bf16x8*)&sK[cur][(((KC) * 4 + l4) * 32 + 16 + l15) * 8]; \
    a1 = __builtin_amdgcn_mfma_f32_16x16x32_bf16(k1, QF, a1, 0, 0, 0); }

  DMA_K(0, 0);
  ushort4 cn0 = *(const ushort4*)(cgrow + (l4 << 2));
  ushort4 cn1 = *(const ushort4*)(cgrow + 16 + (l4 << 2));
  float sum = 0.f;
  for (int kt = 0; kt < NKT; ++kt) {
    const int cur = kt & 1;
    __syncthreads();
    if (kt + 1 < NKT) DMA_K(cur ^ 1, kt + 1);
    ushort4 b0 = cn0, b1 = cn1;
    if (kt + 1 < NKT) {
      cn0 = *(const ushort4*)(cgrow + (kt + 1) * 32 + (l4 << 2));
      cn1 = *(const ushort4*)(cgrow + (kt + 1) * 32 + 16 + (l4 << 2));
    }
    f32x4 a0 = {0.f,0.f,0.f,0.f}, a1 = {0.f,0.f,0.f,0.f};
    QKS(0, qf0) QKS(1, qf1) QKS(2, qf2) QKS(3, qf3)
    sum += __expf(a0[0] * SCALE + bf2f(b0.x));
    sum += __expf(a0[1] * SCALE + bf2f(b0.y));
    sum += __expf(a0[2] * SCALE + bf2f(b0.z));
    sum += __expf(a0[3] * SCALE + bf2f(b0.w));
    sum += __expf(a1[0] * SCALE + bf2f(b1.x));
    sum += __expf(a1[1] * SCALE + bf2f(b1.y));
    sum += __expf(a1[2] * SCALE + bf2f(b1.z));
    sum += __expf(a1[3] * SCALE + bf2f(b1.w));
  }
  sum += __shfl_xor(sum, 16, 64);
  sum += __shfl_xor(sum, 32, 64);
  if (l4 == 0)
    invW[(size_t)bh * LL + q0 + row16 + l15] = 1.0f / sum;
  #undef DMA_K
  #undef QKS
}

// ---------------- pass B: attn_p + O ----------------
__global__ __launch_bounds__(256, 4)
void passB_kernel(const float* __restrict__ q, const unsigned short* __restrict__ kbT,
                  const unsigned short* __restrict__ vtT, const unsigned short* __restrict__ cpw,
                  const float* __restrict__ invW,
                  float* __restrict__ outA, float* __restrict__ outP)
{
  __shared__ unsigned short sK[2][4096];
  __shared__ unsigned short sVt[2][4096];

  const int tid = threadIdx.x;
  const int lane = tid & 63;
  const int wid = tid >> 6;
  const int l15 = lane & 15;
  const int l4 = lane >> 4;

  const int bid = blockIdx.x;
  const int work = ((bid & 7) << 7) | (bid >> 3);
  const int bh = work >> 5;
  const int qt = work & 31;
  const int b = bh >> 4;
  const int q0 = qt * QB;
  const int row16 = wid << 4;

  const unsigned short* kbh = kbT + (size_t)bh * 64 * 4096;
  const unsigned short* vbh = vtT + (size_t)bh * 64 * 4096;
  const unsigned short* cgrow = cpw + (size_t)b * LL * LL + (size_t)(q0 + row16 + l15) * LL;
  float* oA = outA + (size_t)(bh * LL + q0) * DD;
  float* oPr = outP + (size_t)bh * LL * LL + (size_t)(q0 + row16 + l15) * LL;

  const float inv = invW[(size_t)bh * LL + q0 + row16 + l15];

  bf16x8 qf0, qf1, qf2, qf3;
  {
    const float* qs = q + (size_t)(bh * LL + q0 + row16 + l15) * DD + l4 * 8;
    #define LQ(FR, KC) { \
      float4 a = *(const float4*)(qs + (KC) * 32); \
      float4 c = *(const float4*)(qs + (KC) * 32 + 4); \
      FR[0]=(short)f2bf(a.x); FR[1]=(short)f2bf(a.y); FR[2]=(short)f2bf(a.z); FR[3]=(short)f2bf(a.w); \
      FR[4]=(short)f2bf(c.x); FR[5]=(short)f2bf(c.y); FR[6]=(short)f2bf(c.z); FR[7]=(short)f2bf(c.w); }
    LQ(qf0, 0) LQ(qf1, 1) LQ(qf2, 2) LQ(qf3, 3)
    #undef LQ
  }

  #define DMA_K(BUF, KT) do { \
    GLD16(kbh + (size_t)(KT) * 4096 + tid * 8,         &sK[BUF][wid << 9]); \
    GLD16(kbh + (size_t)(KT) * 4096 + (256 + tid) * 8, &sK[BUF][2048 + (wid << 9)]); } while (0)
  #define DMA_V(BUF, KT) do { \
    GLD16(vbh + (size_t)(KT) * 4096 + tid * 8,         &sVt[BUF][wid << 9]); \
    GLD16(vbh + (size_t)(KT) * 4096 + (256 + tid) * 8, &sVt[BUF][2048 + (wid << 9)]); } while (0)

  #define QKS(KC, QF) { \
    bf16x8 k0 = *(const bf16x8*)&sK[cur][(((KC) * 4 + l4) * 32 + l15) * 8]; \
    a0 = __builtin_amdgcn_mfma_f32_16x16x32_bf16(k0, QF, a0, 0, 0, 0); \
    bf16x8 k1 = *(const bf16x8*)&sK[cur][(((KC) * 4 + l4) * 32 + 16 + l15) * 8]; \
    a1 = __builtin_amdgcn_mfma_f32_16x16x32_bf16(k1, QF, a1, 0, 0, 0); }

  DMA_K(0, 0); DMA_V(0, 0);
  ushort4 cn0 = *(const ushort4*)(cgrow + (l4 << 2));
  ushort4 cn1 = *(const ushort4*)(cgrow + 16 + (l4 << 2));
  f32x4 oacc[8];
  #pragma unroll
  for (int dt = 0; dt < 8; ++dt) oacc[dt] = (f32x4){0.f,0.f,0.f,0.f};

  const int srcA = l15 + (((l4 << 1) + 0) & 3) * 16;
  const int srcB = l15 + (((l4 << 1) + 1) & 3) * 16;
  const bool hiTile = (l4 >= 2);

  for (int kt = 0; kt < NKT; ++kt) {
    const int cur = kt & 1;
    __syncthreads();
    if (kt + 1 < NKT) { DMA_K(cur ^ 1, kt + 1); DMA_V(cur ^ 1, kt + 1); }
    ushort4 b0 = cn0, b1 = cn1;
    if (kt + 1 < NKT) {
      cn0 = *(const ushort4*)(cgrow + (kt + 1) * 32 + (l4 << 2));
      cn1 = *(const ushort4*)(cgrow + (kt + 1) * 32 + 16 + (l4 << 2));
    }
    f32x4 a0 = {0.f,0.f,0.f,0.f}, a1 = {0.f,0.f,0.f,0.f};
    QKS(0, qf0) QKS(1, qf1) QKS(2, qf2) QKS(3, qf3)

    f32x4 p0, p1;
    p0[0] = __expf(a0[0] * SCALE + bf2f(b0.x)) * inv;
    p0[1] = __expf(a0[1] * SCALE + bf2f(b0.y)) * inv;
    p0[2] = __expf(a0[2] * SCALE + bf2f(b0.z)) * inv;
    p0[3] = __expf(a0[3] * SCALE + bf2f(b0.w)) * inv;
    p1[0] = __expf(a1[0] * SCALE + bf2f(b1.x)) * inv;
    p1[1] = __expf(a1[1] * SCALE + bf2f(b1.y)) * inv;
    p1[2] = __expf(a1[2] * SCALE + bf2f(b1.z)) * inv;
    p1[3] = __expf(a1[3] * SCALE + bf2f(b1.w)) * inv;

    __builtin_nontemporal_store(p0, (f32x4*)(oPr + kt * 32 + (l4 << 2)));
    __builtin_nontemporal_store(p1, (f32x4*)(oPr + kt * 32 + 16 + (l4 << 2)));

    unsigned d00, d01, d10, d11;
    asm("v_cvt_pk_bf16_f32 %0, %1, %2" : "=v"(d00) : "v"(p0[0]), "v"(p0[1]));
    asm("v_cvt_pk_bf16_f32 %0, %1, %2" : "=v"(d01) : "v"(p0[2]), "v"(p0[3]));
    asm("v_cvt_pk_bf16_f32 %0, %1, %2" : "=v"(d10) : "v"(p1[0]), "v"(p1[1]));
    asm("v_cvt_pk_bf16_f32 %0, %1, %2" : "=v"(d11) : "v"(p1[2]), "v"(p1[3]));
    int a00 = __shfl((int)d00, srcA, 64);
    int a01 = __shfl((int)d01, srcA, 64);
    int a02 = __shfl((int)d00, srcB, 64);
    int a03 = __shfl((int)d01, srcB, 64);
    int b00 = __shfl((int)d10, srcA, 64);
    int b01 = __shfl((int)d11, srcA, 64);
    int b02 = __shfl((int)d10, srcB, 64);
    int b03 = __shfl((int)d11, srcB, 64);
    i32x4 fw;
    fw[0] = hiTile ? b00 : a00;
    fw[1] = hiTile ? b01 : a01;
    fw[2] = hiTile ? b02 : a02;
    fw[3] = hiTile ? b03 : a03;
    bf16x8 aP = __builtin_bit_cast(bf16x8, fw);

    #pragma unroll
    for (int dt = 0; dt < 8; ++dt) {
      bf16x8 bV = *(const bf16x8*)&sVt[cur][(l4 * 128 + dt * 16 + l15) * 8];
      oacc[dt] = __builtin_amdgcn_mfma_f32_16x16x32_bf16(aP, bV, oacc[dt], 0, 0, 0);
    }
  }

  #pragma unroll
  for (int dt = 0; dt < 8; ++dt) {
    #pragma unroll
    for (int r = 0; r < 4; ++r) {
      __builtin_nontemporal_store(oacc[dt][r],
          oA + (size_t)(row16 + (l4 << 2) + r) * DD + dt * 16 + l15);
    }
  }
}

extern "C" void kernel_launch(void* const* d_in, const int* in_sizes, int n_in,
                              void* d_out, int out_size, void* d_ws, size_t ws_size,
                              hipStream_t stream) {
  const float* q = (const float*)d_in[0];
  const float* k = (const float*)d_in[1];
  const float* v = (const float*)d_in[2];
  const int* mask = (const int*)d_in[3];
  const float* probs = (const float*)d_in[4];
  const float* alpha = (const float*)d_in[5];
  float* outA = (float*)d_out;
  float* outP = outA + (size_t)BB * HH * LL * DD;
  unsigned short* kbT = (unsigned short*)d_ws;
  unsigned short* vtT = kbT + (size_t)32 * 64 * 4096;
  unsigned short* cpw = vtT + (size_t)32 * 64 * 4096;
  float* invW = (float*)(cpw + (size_t)BB * LL * LL);
  hipLaunchKernelGGL(prep_kernel, dim3(32 * 64), dim3(256), 0, stream,
                     k, v, mask, probs, alpha, kbT, vtT, cpw);
  hipLaunchKernelGGL(passA_kernel, dim3(BB * HH * (LL / QB)), dim3(256), 0, stream,
                     q, kbT, cpw, invW);
  hipLaunchKernelGGL(passB_kernel, dim3(BB * HH * (LL / QB)), dim3(256), 0, stream,
                     q, kbT, vtT, cpw, invW, outA, outP);
}

// Round 14
// 257.761 us; speedup vs baseline: 2.7397x; 1.0875x over previous
//
#include <hip/hip_runtime.h>

constexpr int BB = 2, HH = 16, LL = 2048, DD = 128;
constexpr int QB = 64, KB = 32, NKT = LL / KB;   // 64 k-tiles
constexpr float SCALE = 0.08838834764831845f;    // 1/sqrt(128)

typedef __attribute__((ext_vector_type(8))) short bf16x8;
typedef __attribute__((ext_vector_type(8))) unsigned short u16x8;
typedef __attribute__((ext_vector_type(4))) float f32x4;
typedef __attribute__((ext_vector_type(4))) int i32x4;

static __device__ __forceinline__ unsigned short f2bf(float f) {
  unsigned int u = __builtin_bit_cast(unsigned int, f);
  u += 0x7fffu + ((u >> 16) & 1u);   // RNE
  return (unsigned short)(u >> 16);
}
static __device__ __forceinline__ float bf2f(unsigned short h) {
  return __builtin_bit_cast(float, (unsigned int)h << 16);
}

#define GLD16(gsrc, ldst) __builtin_amdgcn_global_load_lds( \
    (const __attribute__((address_space(1))) void*)(gsrc), \
    (__attribute__((address_space(3))) void*)(ldst), 16, 0, 0)

// ---------------- prep ----------------
//   kbT tile [16 dslots][32 keys][8 d] (bf16)
//   vtT tile [4 kc][128 d][8 keys]     (bf16)
//   biasT[b][qt][kt][wid][lane][8]     (bf16) lane-packed: wave's per-iter bias
//     = ONE coalesced u16x8/lane; entry j<4 -> key l4*4+j, j>=4 -> 16+l4*4+j-4
__global__ __launch_bounds__(256)
void prep_kernel(const float* __restrict__ k, const float* __restrict__ v,
                 const int* __restrict__ mask, const float* __restrict__ probs,
                 const float* __restrict__ alphap,
                 unsigned short* __restrict__ kbT, unsigned short* __restrict__ vtT,
                 unsigned short* __restrict__ biasW)
{
  __shared__ unsigned short sT[128 * 40];   // V^T tile, 80 B rows
  const int bid = blockIdx.x;
  const int bh = bid >> 6, kt = bid & 63;
  const int t = threadIdx.x;
  const float alpha = alphap[0];
  const size_t tileBase = (size_t)bid * 4096;   // bid == bh*64 + kt
  const float* kg = k + ((size_t)bh * LL + kt * 32) * DD;
  const float* vg = v + ((size_t)bh * LL + kt * 32) * DD;

  // K -> 16B-block-transposed tile
  #pragma unroll
  for (int s = t; s < 512; s += 256) {
    int dsl = s >> 5, key = s & 31;
    const float* src = kg + key * DD + dsl * 8;
    float4 a = *(const float4*)src;
    float4 c = *(const float4*)(src + 4);
    u16x8 w;
    w[0] = f2bf(a.x); w[1] = f2bf(a.y); w[2] = f2bf(a.z); w[3] = f2bf(a.w);
    w[4] = f2bf(c.x); w[5] = f2bf(c.y); w[6] = f2bf(c.z); w[7] = f2bf(c.w);
    *(u16x8*)(kbT + tileBase + (size_t)s * 8) = w;
  }
  // V -> sT (transpose)
  #pragma unroll
  for (int i = 0; i < 4; ++i) {
    int idx = i * 256 + t;
    int key = idx >> 5, d4 = (idx & 31) * 4;
    float4 x = ((const float4*)vg)[idx];
    sT[(d4 + 0) * 40 + key] = f2bf(x.x);
    sT[(d4 + 1) * 40 + key] = f2bf(x.y);
    sT[(d4 + 2) * 40 + key] = f2bf(x.z);
    sT[(d4 + 3) * 40 + key] = f2bf(x.w);
  }
  // biasT: 2 tiles per block (4096 tiles total, 2048 u16 each)
  #pragma unroll
  for (int it = 0; it < 2; ++it) {
    int tileIdx = bid * 2 + it;            // 0..4095
    int b = tileIdx >> 11;
    int rem = tileIdx & 2047;
    int tq = rem >> 6;                     // qt 0..31
    int tk = rem & 63;                     // kt 0..63
    int row = ((t >> 6) << 4) + (t & 15);  // widx*16 + l15
    int kc = ((t >> 4) & 3) * 4;           // l4*4
    const float* pr = probs + (size_t)b * LL * LL + (size_t)(tq * 64 + row) * LL + tk * 32;
    const int* mr = mask + (size_t)b * LL * LL + (size_t)(tq * 64 + row) * LL + tk * 32;
    float4 f0 = *(const float4*)(pr + kc);
    float4 f1 = *(const float4*)(pr + kc + 16);
    int4 m0 = *(const int4*)(mr + kc);
    int4 m1 = *(const int4*)(mr + kc + 16);
    u16x8 o;
    o[0] = f2bf(m0.x ? f0.x * alpha : -1e30f);
    o[1] = f2bf(m0.y ? f0.y * alpha : -1e30f);
    o[2] = f2bf(m0.z ? f0.z * alpha : -1e30f);
    o[3] = f2bf(m0.w ? f0.w * alpha : -1e30f);
    o[4] = f2bf(m1.x ? f1.x * alpha : -1e30f);
    o[5] = f2bf(m1.y ? f1.y * alpha : -1e30f);
    o[6] = f2bf(m1.z ? f1.z * alpha : -1e30f);
    o[7] = f2bf(m1.w ? f1.w * alpha : -1e30f);
    *(u16x8*)(biasW + (size_t)tileIdx * 2048 + t * 8) = o;
  }
  __syncthreads();
  // sT -> vtT tile [kc][d][8]
  #pragma unroll
  for (int s = t; s < 512; s += 256) {
    int kc = s >> 7, d = s & 127;
    u16x8 w = *(const u16x8*)&sT[d * 40 + kc * 8];
    *(u16x8*)(vtT + tileBase + (size_t)s * 8) = w;
  }
}

// ---------------- pass A: rowsums -> invW ----------------
__global__ __launch_bounds__(256, 6)
void passA_kernel(const float* __restrict__ q, const unsigned short* __restrict__ kbT,
                  const unsigned short* __restrict__ biasW, float* __restrict__ invW)
{
  __shared__ unsigned short sK[2][4096];

  const int tid = threadIdx.x;
  const int lane = tid & 63;
  const int wid = tid >> 6;
  const int l15 = lane & 15;
  const int l4 = lane >> 4;

  const int bid = blockIdx.x;
  const int work = ((bid & 7) << 7) | (bid >> 3);
  const int bh = work >> 5;
  const int qt = work & 31;
  const int b = bh >> 4;
  const int q0 = qt * QB;
  const int row16 = wid << 4;

  const unsigned short* kbh = kbT + (size_t)bh * 64 * 4096;
  const unsigned short* bg = biasW + ((size_t)(b * 32 + qt) * 64) * 2048 + (wid << 9) + (lane << 3);

  bf16x8 qf0, qf1, qf2, qf3;
  {
    const float* qs = q + (size_t)(bh * LL + q0 + row16 + l15) * DD + l4 * 8;
    #define LQ(FR, KC) { \
      float4 a = *(const float4*)(qs + (KC) * 32); \
      float4 c = *(const float4*)(qs + (KC) * 32 + 4); \
      FR[0]=(short)f2bf(a.x); FR[1]=(short)f2bf(a.y); FR[2]=(short)f2bf(a.z); FR[3]=(short)f2bf(a.w); \
      FR[4]=(short)f2bf(c.x); FR[5]=(short)f2bf(c.y); FR[6]=(short)f2bf(c.z); FR[7]=(short)f2bf(c.w); }
    LQ(qf0, 0) LQ(qf1, 1) LQ(qf2, 2) LQ(qf3, 3)
    #undef LQ
  }

  #define DMA_K(BUF, KT) do { \
    GLD16(kbh + (size_t)(KT) * 4096 + tid * 8,         &sK[BUF][wid << 9]); \
    GLD16(kbh + (size_t)(KT) * 4096 + (256 + tid) * 8, &sK[BUF][2048 + (wid << 9)]); } while (0)

  #define QKS(KC, QF) { \
    bf16x8 k0 = *(const bf16x8*)&sK[cur][(((KC) * 4 + l4) * 32 + l15) * 8]; \
    a0 = __builtin_amdgcn_mfma_f32_16x16x32_bf16(k0, QF, a0, 0, 0, 0); \
    bf16x8 k1 = *(const bf16x8*)&sK[cur][(((KC) * 4 + l4) * 32 + 16 + l15) * 8]; \
    a1 = __builtin_amdgcn_mfma_f32_16x16x32_bf16(k1, QF, a1, 0, 0, 0); }

  DMA_K(0, 0);
  u16x8 cnb = *(const u16x8*)(bg);
  float sum = 0.f;
  for (int kt = 0; kt < NKT; ++kt) {
    const int cur = kt & 1;
    __syncthreads();
    if (kt + 1 < NKT) DMA_K(cur ^ 1, kt + 1);
    u16x8 bt = cnb;
    if (kt + 1 < NKT) cnb = *(const u16x8*)(bg + (size_t)(kt + 1) * 2048);
    f32x4 a0 = {0.f,0.f,0.f,0.f}, a1 = {0.f,0.f,0.f,0.f};
    QKS(0, qf0) QKS(1, qf1) QKS(2, qf2) QKS(3, qf3)
    sum += __expf(a0[0] * SCALE + bf2f(bt[0]));
    sum += __expf(a0[1] * SCALE + bf2f(bt[1]));
    sum += __expf(a0[2] * SCALE + bf2f(bt[2]));
    sum += __expf(a0[3] * SCALE + bf2f(bt[3]));
    sum += __expf(a1[0] * SCALE + bf2f(bt[4]));
    sum += __expf(a1[1] * SCALE + bf2f(bt[5]));
    sum += __expf(a1[2] * SCALE + bf2f(bt[6]));
    sum += __expf(a1[3] * SCALE + bf2f(bt[7]));
  }
  sum += __shfl_xor(sum, 16, 64);
  sum += __shfl_xor(sum, 32, 64);
  if (l4 == 0)
    invW[(size_t)bh * LL + q0 + row16 + l15] = 1.0f / sum;
  #undef DMA_K
  #undef QKS
}

// ---------------- pass B: attn_p + O ----------------
__global__ __launch_bounds__(256, 4)
void passB_kernel(const float* __restrict__ q, const unsigned short* __restrict__ kbT,
                  const unsigned short* __restrict__ vtT, const unsigned short* __restrict__ biasW,
                  const float* __restrict__ invW,
                  float* __restrict__ outA, float* __restrict__ outP)
{
  __shared__ unsigned short sK[2][4096];
  __shared__ unsigned short sVt[2][4096];

  const int tid = threadIdx.x;
  const int lane = tid & 63;
  const int wid = tid >> 6;
  const int l15 = lane & 15;
  const int l4 = lane >> 4;

  const int bid = blockIdx.x;
  const int work = ((bid & 7) << 7) | (bid >> 3);
  const int bh = work >> 5;
  const int qt = work & 31;
  const int b = bh >> 4;
  const int q0 = qt * QB;
  const int row16 = wid << 4;

  const unsigned short* kbh = kbT + (size_t)bh * 64 * 4096;
  const unsigned short* vbh = vtT + (size_t)bh * 64 * 4096;
  const unsigned short* bg = biasW + ((size_t)(b * 32 + qt) * 64) * 2048 + (wid << 9) + (lane << 3);
  float* oA = outA + (size_t)(bh * LL + q0) * DD;
  float* oPr = outP + (size_t)bh * LL * LL + (size_t)(q0 + row16 + l15) * LL;

  const float inv = invW[(size_t)bh * LL + q0 + row16 + l15];

  bf16x8 qf0, qf1, qf2, qf3;
  {
    const float* qs = q + (size_t)(bh * LL + q0 + row16 + l15) * DD + l4 * 8;
    #define LQ(FR, KC) { \
      float4 a = *(const float4*)(qs + (KC) * 32); \
      float4 c = *(const float4*)(qs + (KC) * 32 + 4); \
      FR[0]=(short)f2bf(a.x); FR[1]=(short)f2bf(a.y); FR[2]=(short)f2bf(a.z); FR[3]=(short)f2bf(a.w); \
      FR[4]=(short)f2bf(c.x); FR[5]=(short)f2bf(c.y); FR[6]=(short)f2bf(c.z); FR[7]=(short)f2bf(c.w); }
    LQ(qf0, 0) LQ(qf1, 1) LQ(qf2, 2) LQ(qf3, 3)
    #undef LQ
  }

  #define DMA_K(BUF, KT) do { \
    GLD16(kbh + (size_t)(KT) * 4096 + tid * 8,         &sK[BUF][wid << 9]); \
    GLD16(kbh + (size_t)(KT) * 4096 + (256 + tid) * 8, &sK[BUF][2048 + (wid << 9)]); } while (0)
  #define DMA_V(BUF, KT) do { \
    GLD16(vbh + (size_t)(KT) * 4096 + tid * 8,         &sVt[BUF][wid << 9]); \
    GLD16(vbh + (size_t)(KT) * 4096 + (256 + tid) * 8, &sVt[BUF][2048 + (wid << 9)]); } while (0)

  #define QKS(KC, QF) { \
    bf16x8 k0 = *(const bf16x8*)&sK[cur][(((KC) * 4 + l4) * 32 + l15) * 8]; \
    a0 = __builtin_amdgcn_mfma_f32_16x16x32_bf16(k0, QF, a0, 0, 0, 0); \
    bf16x8 k1 = *(const bf16x8*)&sK[cur][(((KC) * 4 + l4) * 32 + 16 + l15) * 8]; \
    a1 = __builtin_amdgcn_mfma_f32_16x16x32_bf16(k1, QF, a1, 0, 0, 0); }

  const int srcA = l15 + (((l4 << 1) + 0) & 3) * 16;
  const int srcB = l15 + (((l4 << 1) + 1) & 3) * 16;
  const bool hiTile = (l4 >= 2);

  f32x4 oacc[8];
  #pragma unroll
  for (int dt = 0; dt < 8; ++dt) oacc[dt] = (f32x4){0.f,0.f,0.f,0.f};

  u16x8 cnb;

  // body macro: compute iteration KT from buf cur; prefetches handled by caller
  #define BBODY(KT) do { \
    const int cur = (KT) & 1; \
    u16x8 bt = cnb; \
    if ((KT) + 1 < NKT) cnb = *(const u16x8*)(bg + (size_t)((KT) + 1) * 2048); \
    f32x4 a0 = {0.f,0.f,0.f,0.f}, a1 = {0.f,0.f,0.f,0.f}; \
    QKS(0, qf0) QKS(1, qf1) QKS(2, qf2) QKS(3, qf3) \
    f32x4 p0, p1; \
    p0[0] = __expf(a0[0] * SCALE + bf2f(bt[0])) * inv; \
    p0[1] = __expf(a0[1] * SCALE + bf2f(bt[1])) * inv; \
    p0[2] = __expf(a0[2] * SCALE + bf2f(bt[2])) * inv; \
    p0[3] = __expf(a0[3] * SCALE + bf2f(bt[3])) * inv; \
    p1[0] = __expf(a1[0] * SCALE + bf2f(bt[4])) * inv; \
    p1[1] = __expf(a1[1] * SCALE + bf2f(bt[5])) * inv; \
    p1[2] = __expf(a1[2] * SCALE + bf2f(bt[6])) * inv; \
    p1[3] = __expf(a1[3] * SCALE + bf2f(bt[7])) * inv; \
    __builtin_nontemporal_store(p0, (f32x4*)(oPr + (KT) * 32 + (l4 << 2))); \
    __builtin_nontemporal_store(p1, (f32x4*)(oPr + (KT) * 32 + 16 + (l4 << 2))); \
    unsigned d00, d01, d10, d11; \
    asm("v_cvt_pk_bf16_f32 %0, %1, %2" : "=v"(d00) : "v"(p0[0]), "v"(p0[1])); \
    asm("v_cvt_pk_bf16_f32 %0, %1, %2" : "=v"(d01) : "v"(p0[2]), "v"(p0[3])); \
    asm("v_cvt_pk_bf16_f32 %0, %1, %2" : "=v"(d10) : "v"(p1[0]), "v"(p1[1])); \
    asm("v_cvt_pk_bf16_f32 %0, %1, %2" : "=v"(d11) : "v"(p1[2]), "v"(p1[3])); \
    int a00 = __shfl((int)d00, srcA, 64); \
    int a01 = __shfl((int)d01, srcA, 64); \
    int a02 = __shfl((int)d00, srcB, 64); \
    int a03 = __shfl((int)d01, srcB, 64); \
    int b00 = __shfl((int)d10, srcA, 64); \
    int b01 = __shfl((int)d11, srcA, 64); \
    int b02 = __shfl((int)d10, srcB, 64); \
    int b03 = __shfl((int)d11, srcB, 64); \
    i32x4 fw; \
    fw[0] = hiTile ? b00 : a00; \
    fw[1] = hiTile ? b01 : a01; \
    fw[2] = hiTile ? b02 : a02; \
    fw[3] = hiTile ? b03 : a03; \
    bf16x8 aP = __builtin_bit_cast(bf16x8, fw); \
    _Pragma("unroll") \
    for (int dt = 0; dt < 8; ++dt) { \
      bf16x8 bV = *(const bf16x8*)&sVt[cur][(l4 * 128 + dt * 16 + l15) * 8]; \
      oacc[dt] = __builtin_amdgcn_mfma_f32_16x16x32_bf16(aP, bV, oacc[dt], 0, 0, 0); \
    } \
  } while (0)

  // prologue: bias first, then DMA (stores later stay the newest-2 ops)
  cnb = *(const u16x8*)(bg);
  DMA_K(0, 0); DMA_V(0, 0);
  asm volatile("s_waitcnt vmcnt(0)\n\ts_barrier" ::: "memory");
  // iter 0 (no stores outstanding yet, but uniform handling after this)
  DMA_K(1, 1); DMA_V(1, 1);
  BBODY(0);
  for (int kt = 1; kt < NKT; ++kt) {
    // counted wait: all-but-2 (the two nt-stores) complete -> DMA(kt)+bias done,
    // stores keep draining in background
    asm volatile("s_waitcnt vmcnt(2)\n\ts_barrier" ::: "memory");
    if (kt + 1 < NKT) {
      const int c2 = (kt + 1) & 1;
      DMA_K(c2, kt + 1); DMA_V(c2, kt + 1);
    }
    BBODY(kt);
  }

  #pragma unroll
  for (int dt = 0; dt < 8; ++dt) {
    #pragma unroll
    for (int r = 0; r < 4; ++r) {
      __builtin_nontemporal_store(oacc[dt][r],
          oA + (size_t)(row16 + (l4 << 2) + r) * DD + dt * 16 + l15);
    }
  }
}

extern "C" void kernel_launch(void* const* d_in, const int* in_sizes, int n_in,
                              void* d_out, int out_size, void* d_ws, size_t ws_size,
                              hipStream_t stream) {
  const float* q = (const float*)d_in[0];
  const float* k = (const float*)d_in[1];
  const float* v = (const float*)d_in[2];
  const int* mask = (const int*)d_in[3];
  const float* probs = (const float*)d_in[4];
  const float* alpha = (const float*)d_in[5];
  float* outA = (float*)d_out;
  float* outP = outA + (size_t)BB * HH * LL * DD;
  unsigned short* kbT = (unsigned short*)d_ws;
  unsigned short* vtT = kbT + (size_t)32 * 64 * 4096;
  unsigned short* biasW = vtT + (size_t)32 * 64 * 4096;
  float* invW = (float*)(biasW + (size_t)4096 * 2048);
  hipLaunchKernelGGL(prep_kernel, dim3(32 * 64), dim3(256), 0, stream,
                     k, v, mask, probs, alpha, kbT, vtT, biasW);
  hipLaunchKernelGGL(passA_kernel, dim3(BB * HH * (LL / QB)), dim3(256), 0, stream,
                     q, kbT, biasW, invW);
  hipLaunchKernelGGL(passB_kernel, dim3(BB * HH * (LL / QB)), dim3(256), 0, stream,
                     q, kbT, vtT, biasW, invW, outA, outP);
}